// Round 11
// baseline (380.909 us; speedup 1.0000x reference)
//
#include <hip/hip_runtime.h>
#include <cstdint>
#include <cstddef>

#define B_SZ 4
#define T_SZ 2048
#define NH 16
#define HD 64
#define CD 1024
#define MROWS (B_SZ*T_SZ)
#define NEG_BIG (-1e30f)
// 0.125 (1/sqrt(64)) * log2(e): fold softmax base-2 conversion into Q prescale
#define Q_SCALE 0.180336880f

typedef __bf16 bf16x8 __attribute__((ext_vector_type(8)));
typedef __bf16 bf16x4 __attribute__((ext_vector_type(4)));
typedef short s16x4 __attribute__((ext_vector_type(4)));
typedef float f32x4 __attribute__((ext_vector_type(4)));

typedef __attribute__((address_space(3))) void* as3p;
typedef const __attribute__((address_space(1))) void* as1p;

__device__ __forceinline__ void glds16(const void* g, void* l) {
  __builtin_amdgcn_global_load_lds((as1p)g, (as3p)l, 16, 0, 0);
}

// ---------------------------------------------------------------------------
// Dtype discriminator (fp32 vs bf16 input encoding). flag=1 -> bf16.
// ---------------------------------------------------------------------------
__global__ __launch_bounds__(256) void detect_dtype(const uint32_t* __restrict__ x,
                                                    int* __restrict__ flag) {
  __shared__ int cnt[256];
  const int t = threadIdx.x;
  int c = 0;
  for (int i = 0; i < 4; i++) {
    uint32_t w = x[t * 4 + i];
    uint32_t e = (w >> 7) & 0xFF;
    c += (e >= 100 && e <= 140) ? 1 : 0;
  }
  cnt[t] = c;
  __syncthreads();
  for (int s = 128; s > 0; s >>= 1) {
    if (t < s) cnt[t] += cnt[t + s];
    __syncthreads();
  }
  if (t == 0) flag[0] = (cnt[0] > 700) ? 1 : 0;
}

__device__ __forceinline__ bf16x8 cvt8(const void* src, int isbf, size_t i8) {
  bf16x8 o;
  if (isbf) {
    o = ((const bf16x8*)src)[i8];
  } else {
    const float4* s = (const float4*)((const float*)src + i8 * 8);
    float4 a = s[0], b = s[1];
    o[0] = (__bf16)a.x; o[1] = (__bf16)a.y; o[2] = (__bf16)a.z; o[3] = (__bf16)a.w;
    o[4] = (__bf16)b.x; o[5] = (__bf16)b.y; o[6] = (__bf16)b.z; o[7] = (__bf16)b.w;
  }
  return o;
}

__global__ __launch_bounds__(256) void conv_in(const void* __restrict__ src,
                                               const int* __restrict__ flag,
                                               __bf16* __restrict__ dst, int n8) {
  int i = blockIdx.x * 256 + threadIdx.x;
  if (i >= n8) return;
  ((bf16x8*)dst)[i] = cvt8(src, flag[0], i);
}

struct Ptr4 { const void* s[4]; __bf16* d[4]; };

__global__ __launch_bounds__(256) void conv_b4(Ptr4 p, const int* __restrict__ flag) {
  int i = threadIdx.x;
  if (i >= CD / 8) return;
  int which = blockIdx.x;
  ((bf16x8*)p.d[which])[i] = cvt8(p.s[which], flag[0], i);
}

// 4 weight matrices 1024x1024 -> transposed canonical bf16 (z selects)
__global__ __launch_bounds__(256) void transpose_conv4(Ptr4 p,
                                                       const int* __restrict__ flag) {
  __shared__ __align__(16) __bf16 tile[64 * 72];
  const void* W = p.s[blockIdx.z];
  __bf16* WT = p.d[blockIdx.z];
  const int t = threadIdx.x;
  const int r0 = blockIdx.y * 64, c0 = blockIdx.x * 64;
  const int rr = t >> 3, c8 = (t & 7) * 8;
  const int isbf = flag[0];
  for (int pp = 0; pp < 2; pp++) {
    int r = pp * 32 + rr;
    *(bf16x8*)(tile + r * 72 + c8) =
        cvt8(W, isbf, ((size_t)(r0 + r) * CD + c0 + c8) / 8);
  }
  __syncthreads();
  for (int pp = 0; pp < 2; pp++) {
    int cc = pp * 32 + rr;
    bf16x8 o;
    for (int j = 0; j < 8; j++) o[j] = tile[(c8 + j) * 72 + cc];
    *(bf16x8*)(WT + (size_t)(c0 + cc) * CD + r0 + c8) = o;
  }
}

// ---------------------------------------------------------------------------
// Fused QKV GEMM: C[8192, 3072] = x @ [WqT;WkT;WvT]^T + bias.
// bn 0-7 -> Q, 8-15 -> K, 16-23 -> V (seg uniform per block).
// R9 structure (single 32KB buffer, 2 barriers/K-step, default block order
// — R10 showed dbuf=neutral, XCD-swizzle=worse FETCH).
// __launch_bounds__(256,3): cap total regs at 170 (acc=64 AGPR + ~106 VGPR)
// -> 3 blocks/CU (was 2, register-limited at 180 total). The extra resident
// wave per SIMD hides the staging drain at the barrier — that latency, not
// the barrier count, was the 29%-MfmaUtil stall (R10 falsified the
// barrier-drain theory; occupancy identical across LDS 32/64KB).
// XOR-swizzled LDS via pre-swizzled global source; reads XOR (l15&7)*8.
// Q/K use swapped MFMA (C^T frags) -> bf16x4 epilogue stores.
// ---------------------------------------------------------------------------
__global__ __launch_bounds__(256, 3) void gemm_qkv(
    const __bf16* __restrict__ A, const __bf16* __restrict__ BT,
    const __bf16* __restrict__ bias,
    __bf16* __restrict__ Qb, __bf16* __restrict__ Kb, __bf16* __restrict__ Vt) {
  __shared__ __align__(16) __bf16 As[128 * 64];
  __shared__ __align__(16) __bf16 Bs[128 * 64];
  const int tid = threadIdx.x;
  const int w = tid >> 6, lane = tid & 63;
  const int l15 = lane & 15, quad = lane >> 4;
  const int wm = w & 1, wn = w >> 1;
  const int bm = blockIdx.y, bn = blockIdx.x;
  const bool swapped = (bn < 16);        // Q and K segments

  f32x4 acc[4][4];
  for (int i = 0; i < 4; i++)
    for (int j = 0; j < 4; j++) acc[i][j] = (f32x4)0.f;

  const int srow = lane >> 3, scol = (lane & 7) * 8;
  const int scolsw = scol ^ (srow * 8);          // pre-swizzled source col
  const __bf16* Abase = A + (size_t)(bm * 128) * CD;
  const __bf16* Bbase = BT + (size_t)(bn * 128) * CD;

  const int swz = (l15 & 7) * 8;                  // read-side swizzle
  for (int k0 = 0; k0 < CD; k0 += 64) {
    __syncthreads();
    for (int p = 0; p < 4; p++) {
      int seg = p * 4 + w;
      int row = seg * 8 + srow;
      glds16(Abase + (size_t)row * CD + k0 + scolsw, (char*)As + seg * 1024);
      glds16(Bbase + (size_t)row * CD + k0 + scolsw, (char*)Bs + seg * 1024);
    }
    __syncthreads();
    for (int kc = 0; kc < 2; kc++) {
      const int koff = (kc * 32 + quad * 8) ^ swz;
      bf16x8 af[4], bfr[4];
      for (int mt = 0; mt < 4; mt++)
        af[mt] = *(const bf16x8*)(As + (wm * 64 + mt * 16 + l15) * 64 + koff);
      for (int nt = 0; nt < 4; nt++)
        bfr[nt] = *(const bf16x8*)(Bs + (wn * 64 + nt * 16 + l15) * 64 + koff);
      if (swapped) {
        for (int mt = 0; mt < 4; mt++)
          for (int nt = 0; nt < 4; nt++)
            acc[mt][nt] = __builtin_amdgcn_mfma_f32_16x16x32_bf16(
                bfr[nt], af[mt], acc[mt][nt], 0, 0, 0);
      } else {
        for (int mt = 0; mt < 4; mt++)
          for (int nt = 0; nt < 4; nt++)
            acc[mt][nt] = __builtin_amdgcn_mfma_f32_16x16x32_bf16(
                af[mt], bfr[nt], acc[mt][nt], 0, 0, 0);
      }
    }
  }

  if (swapped) {
    // C^T frags: reg r -> channel d0+r, l15 -> token. 8B stores.
    const int hq = (bn & 7) * 2 + wn;          // head (uniform)
    const int bq_ = bm >> 4;                   // batch (uniform)
    const int tokb = (bm & 15) * 128 + wm * 64;
    __bf16* dst = (bn < 8) ? Qb : Kb;
    const float sc = (bn < 8) ? Q_SCALE : 1.f;
    for (int nt = 0; nt < 4; nt++) {
      const int d0 = nt * 16 + quad * 4;
      bf16x4 bv4 = *(const bf16x4*)(bias + bn * 128 + wn * 64 + d0);
      for (int mt = 0; mt < 4; mt++) {
        int tok = tokb + mt * 16 + l15;
        bf16x4 o;
        for (int r = 0; r < 4; r++)
          o[r] = (__bf16)((acc[mt][nt][r] + (float)bv4[r]) * sc);
        *(bf16x4*)(dst + ((size_t)(bq_ * NH + hq) * T_SZ + tok) * HD + d0) = o;
      }
    }
  } else {
    // V: normal frags (reg r -> token), store V^T [B*H, 64, T] 8B along tok
    for (int nt = 0; nt < 4; nt++) {
      int col = bn * 128 + wn * 64 + nt * 16 + l15;
      int c = col & 1023, h = c >> 6, d = c & 63;
      float bv = (float)bias[col];
      for (int mt = 0; mt < 4; mt++) {
        int row0 = bm * 128 + wm * 64 + mt * 16 + quad * 4;
        int b = row0 >> 11, tok0 = row0 & 2047;
        bf16x4 o;
        for (int r = 0; r < 4; r++) o[r] = (__bf16)(acc[mt][nt][r] + bv);
        *(bf16x4*)(Vt + ((size_t)((b << 4) + h) * HD + d) * T_SZ + tok0) = o;
      }
    }
  }
}

// ---------------------------------------------------------------------------
// Out-proj GEMM: d_out[8192,1024] = Yb @ WoT^T + bo, output dtype per flag.
// R9 structure + __launch_bounds__(256,3) (same occupancy fix as gemm_qkv).
// ---------------------------------------------------------------------------
__global__ __launch_bounds__(256, 3) void gemm_out(
    const __bf16* __restrict__ A, const __bf16* __restrict__ BT,
    const __bf16* __restrict__ bias, void* __restrict__ Out,
    const int* __restrict__ flag) {
  __shared__ __align__(16) __bf16 As[128 * 64];
  __shared__ __align__(16) __bf16 Bs[128 * 64];
  const int tid = threadIdx.x;
  const int w = tid >> 6, lane = tid & 63;
  const int l15 = lane & 15, quad = lane >> 4;
  const int wm = w & 1, wn = w >> 1;
  const int bm = blockIdx.y, bn = blockIdx.x;

  f32x4 acc[4][4];
  for (int i = 0; i < 4; i++)
    for (int j = 0; j < 4; j++) acc[i][j] = (f32x4)0.f;

  const int srow = lane >> 3, scol = (lane & 7) * 8;
  const int scolsw = scol ^ (srow * 8);
  const __bf16* Abase = A + (size_t)(bm * 128) * CD;
  const __bf16* Bbase = BT + (size_t)(bn * 128) * CD;

  const int swz = (l15 & 7) * 8;
  for (int k0 = 0; k0 < CD; k0 += 64) {
    __syncthreads();
    for (int p = 0; p < 4; p++) {
      int seg = p * 4 + w;
      int row = seg * 8 + srow;
      glds16(Abase + (size_t)row * CD + k0 + scolsw, (char*)As + seg * 1024);
      glds16(Bbase + (size_t)row * CD + k0 + scolsw, (char*)Bs + seg * 1024);
    }
    __syncthreads();
    for (int kc = 0; kc < 2; kc++) {
      const int koff = (kc * 32 + quad * 8) ^ swz;
      bf16x8 af[4], bfr[4];
      for (int mt = 0; mt < 4; mt++)
        af[mt] = *(const bf16x8*)(As + (wm * 64 + mt * 16 + l15) * 64 + koff);
      for (int nt = 0; nt < 4; nt++)
        bfr[nt] = *(const bf16x8*)(Bs + (wn * 64 + nt * 16 + l15) * 64 + koff);
      // swapped: C^T frags (4 consecutive cols per lane's regs)
      for (int mt = 0; mt < 4; mt++)
        for (int nt = 0; nt < 4; nt++)
          acc[mt][nt] = __builtin_amdgcn_mfma_f32_16x16x32_bf16(
              bfr[nt], af[mt], acc[mt][nt], 0, 0, 0);
    }
  }

  const int isbf = flag[0];
  for (int nt = 0; nt < 4; nt++) {
    const int colb = bn * 128 + wn * 64 + nt * 16 + quad * 4;
    bf16x4 bv4 = *(const bf16x4*)(bias + colb);
    for (int mt = 0; mt < 4; mt++) {
      int row = bm * 128 + wm * 64 + mt * 16 + l15;
      if (isbf) {
        bf16x4 o;
        for (int r = 0; r < 4; r++)
          o[r] = (__bf16)(acc[mt][nt][r] + (float)bv4[r]);
        *(bf16x4*)((__bf16*)Out + (size_t)row * CD + colb) = o;
      } else {
        f32x4 o;
        for (int r = 0; r < 4; r++) o[r] = acc[mt][nt][r] + (float)bv4[r];
        *(f32x4*)((float*)Out + (size_t)row * CD + colb) = o;
      }
    }
  }
}

// ---------------------------------------------------------------------------
// Flash attention, causal, transposed-S. Q pre-scaled by 0.125*log2e.
// (unchanged from Round 7/9 — passed; already single-barrier dbuf)
// ---------------------------------------------------------------------------
__global__ __launch_bounds__(512, 4) void attn(
    const __bf16* __restrict__ Q, const __bf16* __restrict__ K,
    const __bf16* __restrict__ Vt, __bf16* __restrict__ Y) {
  __shared__ __align__(16) __bf16 Ks[2][128 * 64];   // swizzled, 16KB each
  __shared__ __align__(16) __bf16 Vs[2][64 * 140];   // [d][key], pitch 140

  const int tid = threadIdx.x, w = tid >> 6, lane = tid & 63;
  const int l15 = lane & 15, quad = lane >> 4;
  const int lid = blockIdx.x + 8 * blockIdx.y;   // gridDim.x == 8
  const int bh = lid & 63;                       // XCD = lid%8 = bh%8
  const int pairi = lid >> 6;                    // 0..7

  const __bf16* Qbh = Q + (size_t)bh * T_SZ * HD;
  const __bf16* Kbh = K + (size_t)bh * T_SZ * HD;
  const __bf16* Vbh = Vt + (size_t)bh * HD * T_SZ;

  const int srow = tid >> 3;          // 0..63
  const int scol = (tid & 7) * 8;     // 0..56
  const int ksrc = scol ^ ((srow & 7) * 8);   // pre-swizzled source column
  const int b = bh >> 4, h = bh & 15;

  bf16x4 ones;
  for (int r = 0; r < 4; r++) ones[r] = (__bf16)1.0f;

  for (int ph = 0; ph < 2; ph++) {
    const int tq = ph ? (15 - pairi) : pairi;
    const int q0 = tq * 128;
    const int niter = tq + 1;
    const int qw = q0 + w * 16;       // wave's first q row

    __syncthreads();   // prior phase fully done with LDS
    // prologue: stage KV tile 0 into buffer 0 (K async, V via regs)
    glds16(Kbh + (size_t)srow * HD + ksrc, (char*)Ks[0] + w * 1024);
    glds16(Kbh + (size_t)(64 + srow) * HD + ksrc,
           (char*)Ks[0] + 8192 + w * 1024);
    {
      bf16x8 va = *(const bf16x8*)(Vbh + (size_t)srow * T_SZ + scol);
      bf16x8 vb = *(const bf16x8*)(Vbh + (size_t)srow * T_SZ + 64 + scol);
      *(bf16x4*)(Vs[0] + srow * 140 + scol)          = ((bf16x4*)&va)[0];
      *(bf16x4*)(Vs[0] + srow * 140 + scol + 4)      = ((bf16x4*)&va)[1];
      *(bf16x4*)(Vs[0] + srow * 140 + 64 + scol)     = ((bf16x4*)&vb)[0];
      *(bf16x4*)(Vs[0] + srow * 140 + 64 + scol + 4) = ((bf16x4*)&vb)[1];
    }

    // Q fragments (B-operand: n=l15->q, k=quad*8+j->d)
    bf16x8 aq[2];
    for (int kc = 0; kc < 2; kc++)
      aq[kc] = *(const bf16x8*)(
          Qbh + (size_t)(qw + l15) * HD + kc * 32 + quad * 8);

    f32x4 acco[4];   // O^T tiles [d16 x q16]: row d=quad*4+r, col q=l15
    for (int dt = 0; dt < 4; dt++) acco[dt] = (f32x4)0.f;
    f32x4 accl = (f32x4)0.f;   // ones-row MFMA: accl[0] = sum_k P[k][q=l15]
    float m_ = NEG_BIG;

    for (int it = 0; it < niter; it++) {
      const int cur = it & 1;
      const int kv0 = it * 128;
      __syncthreads();   // staging for cur drained (syncthreads waits vmcnt)

      // issue async staging of next K tile + reg-prefetch next V tile
      bf16x8 vna, vnb;
      const bool havenext = (it + 1 < niter);
      if (havenext) {
        int kv1 = kv0 + 128;
        glds16(Kbh + (size_t)(kv1 + srow) * HD + ksrc,
               (char*)Ks[cur ^ 1] + w * 1024);
        glds16(Kbh + (size_t)(kv1 + 64 + srow) * HD + ksrc,
               (char*)Ks[cur ^ 1] + 8192 + w * 1024);
        vna = *(const bf16x8*)(Vbh + (size_t)srow * T_SZ + kv1 + scol);
        vnb = *(const bf16x8*)(Vbh + (size_t)srow * T_SZ + kv1 + 64 + scol);
      }

      // waves whose 16 q rows are entirely below this KV tile skip compute
      if (kv0 <= qw + 15) {
        const __bf16* Ksc = Ks[cur];
        const __bf16* Vsc = Vs[cur];

        // S^T = K Q^T : tiles [key16 x q16]; row key=quad*4+r, col q=l15
        f32x4 accs[8];
        for (int nt = 0; nt < 8; nt++) accs[nt] = (f32x4)0.f;
        const int swz = (l15 & 7) * 8;     // K read swizzle (row&7 == l15&7)
        for (int kc = 0; kc < 2; kc++)
          for (int nt = 0; nt < 8; nt++) {
            bf16x8 ak = *(const bf16x8*)(
                Ksc + (nt * 16 + l15) * 64 + ((kc * 32 + quad * 8) ^ swz));
            accs[nt] = __builtin_amdgcn_mfma_f32_16x16x32_bf16(
                ak, aq[kc], accs[nt], 0, 0, 0);
          }

        // causal mask (only the diagonal tile: kv0 == q0)
        if (kv0 + 127 > qw) {
          int qg = qw + l15;
          for (int nt = 0; nt < 8; nt++) {
            int kg0 = kv0 + nt * 16 + quad * 4;
            for (int r = 0; r < 4; r++)
              if (kg0 + r > qg) accs[nt][r] = NEG_BIG;
          }
        }

        // local max: per-tile max4 then tree + cross-quad shfl_xor
        float tm[8];
        for (int nt = 0; nt < 8; nt++)
          tm[nt] = fmaxf(fmaxf(accs[nt][0], accs[nt][1]),
                         fmaxf(accs[nt][2], accs[nt][3]));
        float u0 = fmaxf(fmaxf(tm[0], tm[1]), fmaxf(tm[2], tm[3]));
        float u1 = fmaxf(fmaxf(tm[4], tm[5]), fmaxf(tm[6], tm[7]));
        float mloc = fmaxf(u0, u1);
        mloc = fmaxf(mloc, __shfl_xor(mloc, 16));
        mloc = fmaxf(mloc, __shfl_xor(mloc, 32));

        // exact skip: if no lane's max grew, alpha==1 -> rescale is a no-op
        if (!__all(mloc <= m_)) {
          float mnew = fmaxf(m_, mloc);
          float alpha = __builtin_amdgcn_exp2f(m_ - mnew);
          m_ = mnew;
          accl[0] *= alpha;
          for (int dt = 0; dt < 4; dt++)
            for (int r = 0; r < 4; r++) acco[dt][r] *= alpha;
        }

        // P^T = exp2(S^T - m): stays in regs as x16 B-operand fragments
        bf16x4 pf[8];
        for (int nt = 0; nt < 8; nt++)
          for (int r = 0; r < 4; r++)
            pf[nt][r] = (__bf16)__builtin_amdgcn_exp2f(accs[nt][r] - m_);

        // O^T += V^T P^T; l-row via ones-A MFMA (dt==4 virtual tile)
#pragma unroll
        for (int nt = 0; nt < 8; nt++) {
          accl = __builtin_amdgcn_mfma_f32_16x16x16bf16_1k(
              *(const s16x4*)&ones, *(const s16x4*)&pf[nt], accl, 0, 0, 0);
#pragma unroll
          for (int dt = 0; dt < 4; dt++) {
            bf16x4 av = *(const bf16x4*)(
                Vsc + (dt * 16 + l15) * 140 + nt * 16 + quad * 4);
            acco[dt] = __builtin_amdgcn_mfma_f32_16x16x16bf16_1k(
                *(const s16x4*)&av, *(const s16x4*)&pf[nt], acco[dt], 0, 0, 0);
          }
        }
      }

      // stage prefetched V tile into the other buffer (iter end; the
      // vmcnt wait here also covers the K glds16 issued at iter start)
      if (havenext) {
        int nb = cur ^ 1;
        *(bf16x4*)(Vs[nb] + srow * 140 + scol)          = ((bf16x4*)&vna)[0];
        *(bf16x4*)(Vs[nb] + srow * 140 + scol + 4)      = ((bf16x4*)&vna)[1];
        *(bf16x4*)(Vs[nb] + srow * 140 + 64 + scol)     = ((bf16x4*)&vnb)[0];
        *(bf16x4*)(Vs[nb] + srow * 140 + 64 + scol + 4) = ((bf16x4*)&vnb)[1];
      }
    }

    // epilogue: O^T -> Y [B*T, 1024], 8B stores (4 consecutive d)
    {
      float rcp = 1.f / accl[0];
      int qg = qw + l15;
      size_t base = ((size_t)(b * T_SZ + qg)) * CD + h * HD + quad * 4;
      for (int dt = 0; dt < 4; dt++) {
        bf16x4 o;
        for (int r = 0; r < 4; r++) o[r] = (__bf16)(acco[dt][r] * rcp);
        *(bf16x4*)(Y + base + dt * 16) = o;
      }
    }
  }
}

// ---------------------------------------------------------------------------
extern "C" void kernel_launch(void* const* d_in, const int* in_sizes, int n_in,
                              void* d_out, int out_size, void* d_ws, size_t ws_size,
                              hipStream_t stream) {
  (void)in_sizes; (void)n_in; (void)out_size; (void)ws_size;
  const void* x  = d_in[0];
  const void* Wq = d_in[2];
  const void* bq = d_in[3];
  const void* Wk = d_in[4];
  const void* bk = d_in[5];
  const void* Wv = d_in[6];
  const void* bv = d_in[7];
  const void* Wo = d_in[8];
  const void* bo = d_in[9];

  char* ws = (char*)d_ws;
  const size_t MB = 1024 * 1024;
  __bf16* WqkvT = (__bf16*)(ws + 0 * MB);          // [3072, 1024]
  __bf16* WoT   = (__bf16*)(ws + 6 * MB);
  __bf16* bqkvc = (__bf16*)(ws + 8 * MB);          // [3072]
  __bf16* boc   = (__bf16*)(ws + 8 * MB + 8192);
  int*    flag  = (int*)   (ws + 8 * MB + 65536);
  __bf16* xc    = (__bf16*)(ws + 9 * MB);          // [8192,1024]; reused as Yb
  __bf16* Qb    = (__bf16*)(ws + 25 * MB);         // [B*H,T,64] pre-scaled
  __bf16* Kb    = (__bf16*)(ws + 41 * MB);
  __bf16* Vt_g  = (__bf16*)(ws + 57 * MB);         // [B*H,64,T]
  __bf16* Yb    = xc;                              // xc dead after QKV GEMM

  dim3 tb(256);
  detect_dtype<<<1, tb, 0, stream>>>((const uint32_t*)x, flag);

  conv_in<<<4096, tb, 0, stream>>>(x, flag, xc, MROWS * CD / 8);
  Ptr4 pb = {{bq, bk, bv, bo}, {bqkvc, bqkvc + CD, bqkvc + 2 * CD, boc}};
  conv_b4<<<4, tb, 0, stream>>>(pb, flag);
  Ptr4 pw = {{Wq, Wk, Wv, Wo},
             {WqkvT, WqkvT + (size_t)CD * CD, WqkvT + 2 * (size_t)CD * CD, WoT}};
  transpose_conv4<<<dim3(16, 16, 4), tb, 0, stream>>>(pw, flag);

  gemm_qkv<<<dim3(24, MROWS / 128), tb, 0, stream>>>(xc, WqkvT, bqkvc, Qb, Kb, Vt_g);

  attn<<<dim3(8, B_SZ * NH), dim3(512), 0, stream>>>(Qb, Kb, Vt_g, Yb);

  gemm_out<<<dim3(CD / 128, MROWS / 128), tb, 0, stream>>>(Yb, WoT, boc, d_out, flag);
}

// Round 12
// 277.694 us; speedup vs baseline: 1.3717x; 1.3717x over previous
//
#include <hip/hip_runtime.h>
#include <cstdint>
#include <cstddef>

#define B_SZ 4
#define T_SZ 2048
#define NH 16
#define HD 64
#define CD 1024
#define MROWS (B_SZ*T_SZ)
#define NEG_BIG (-1e30f)
// 0.125 (1/sqrt(64)) * log2(e): fold softmax base-2 conversion into Q prescale
#define Q_SCALE 0.180336880f

typedef __bf16 bf16x8 __attribute__((ext_vector_type(8)));
typedef __bf16 bf16x4 __attribute__((ext_vector_type(4)));
typedef short s16x4 __attribute__((ext_vector_type(4)));
typedef float f32x4 __attribute__((ext_vector_type(4)));

typedef __attribute__((address_space(3))) void* as3p;
typedef const __attribute__((address_space(1))) void* as1p;

__device__ __forceinline__ void glds16(const void* g, void* l) {
  __builtin_amdgcn_global_load_lds((as1p)g, (as3p)l, 16, 0, 0);
}

// ---------------------------------------------------------------------------
// Dtype discriminator (fp32 vs bf16 input encoding). flag=1 -> bf16.
// ---------------------------------------------------------------------------
__global__ __launch_bounds__(256) void detect_dtype(const uint32_t* __restrict__ x,
                                                    int* __restrict__ flag) {
  __shared__ int cnt[256];
  const int t = threadIdx.x;
  int c = 0;
  for (int i = 0; i < 4; i++) {
    uint32_t w = x[t * 4 + i];
    uint32_t e = (w >> 7) & 0xFF;
    c += (e >= 100 && e <= 140) ? 1 : 0;
  }
  cnt[t] = c;
  __syncthreads();
  for (int s = 128; s > 0; s >>= 1) {
    if (t < s) cnt[t] += cnt[t + s];
    __syncthreads();
  }
  if (t == 0) flag[0] = (cnt[0] > 700) ? 1 : 0;
}

__device__ __forceinline__ bf16x8 cvt8(const void* src, int isbf, size_t i8) {
  bf16x8 o;
  if (isbf) {
    o = ((const bf16x8*)src)[i8];
  } else {
    const float4* s = (const float4*)((const float*)src + i8 * 8);
    float4 a = s[0], b = s[1];
    o[0] = (__bf16)a.x; o[1] = (__bf16)a.y; o[2] = (__bf16)a.z; o[3] = (__bf16)a.w;
    o[4] = (__bf16)b.x; o[5] = (__bf16)b.y; o[6] = (__bf16)b.z; o[7] = (__bf16)b.w;
  }
  return o;
}

__global__ __launch_bounds__(256) void conv_in(const void* __restrict__ src,
                                               const int* __restrict__ flag,
                                               __bf16* __restrict__ dst, int n8) {
  int i = blockIdx.x * 256 + threadIdx.x;
  if (i >= n8) return;
  ((bf16x8*)dst)[i] = cvt8(src, flag[0], i);
}

struct Ptr4 { const void* s[4]; __bf16* d[4]; };

__global__ __launch_bounds__(256) void conv_b4(Ptr4 p, const int* __restrict__ flag) {
  int i = threadIdx.x;
  if (i >= CD / 8) return;
  int which = blockIdx.x;
  ((bf16x8*)p.d[which])[i] = cvt8(p.s[which], flag[0], i);
}

// 4 weight matrices 1024x1024 -> transposed canonical bf16 (z selects)
__global__ __launch_bounds__(256) void transpose_conv4(Ptr4 p,
                                                       const int* __restrict__ flag) {
  __shared__ __align__(16) __bf16 tile[64 * 72];
  const void* W = p.s[blockIdx.z];
  __bf16* WT = p.d[blockIdx.z];
  const int t = threadIdx.x;
  const int r0 = blockIdx.y * 64, c0 = blockIdx.x * 64;
  const int rr = t >> 3, c8 = (t & 7) * 8;
  const int isbf = flag[0];
  for (int pp = 0; pp < 2; pp++) {
    int r = pp * 32 + rr;
    *(bf16x8*)(tile + r * 72 + c8) =
        cvt8(W, isbf, ((size_t)(r0 + r) * CD + c0 + c8) / 8);
  }
  __syncthreads();
  for (int pp = 0; pp < 2; pp++) {
    int cc = pp * 32 + rr;
    bf16x8 o;
    for (int j = 0; j < 8; j++) o[j] = tile[(c8 + j) * 72 + cc];
    *(bf16x8*)(WT + (size_t)(c0 + cc) * CD + r0 + c8) = o;
  }
}

// ---------------------------------------------------------------------------
// Fused QKV GEMM: C[8192, 3072] = x @ [WqT;WkT;WvT]^T + bias.
// bn 0-7 -> Q, 8-15 -> K, 16-23 -> V (seg uniform per block).
// 512 threads / 8 waves (2M x 4N), wave tile 64x32: acc[4][2] = 32 AGPR
// (was 64) -> natural regs/wave ~<=128 -> 2 blocks/CU = 4 waves/SIMD
// (R9 was 2: register-limited at ~180/wave with the 64x64 wave tile).
// NO launch-bounds reg cap — R11 proved capping below natural usage spills
// the K-loop catastrophically (WRITE_SIZE 49->487MB).
// R9 loop structure (single 32KB buffer, 2 barriers/K-step; R10 showed
// dbuf=neutral, XCD-swizzle=worse). XOR-swizzled LDS via pre-swizzled
// global source; reads XOR (l15&7)*8. Q/K swapped MFMA -> bf16x4 stores.
// ---------------------------------------------------------------------------
__global__ __launch_bounds__(512) void gemm_qkv(
    const __bf16* __restrict__ A, const __bf16* __restrict__ BT,
    const __bf16* __restrict__ bias,
    __bf16* __restrict__ Qb, __bf16* __restrict__ Kb, __bf16* __restrict__ Vt) {
  __shared__ __align__(16) __bf16 As[128 * 64];
  __shared__ __align__(16) __bf16 Bs[128 * 64];
  const int tid = threadIdx.x;
  const int w = tid >> 6, lane = tid & 63;
  const int l15 = lane & 15, quad = lane >> 4;
  const int wm = w & 1, wn = w >> 1;             // wn 0..3
  const int bm = blockIdx.y, bn = blockIdx.x;
  const bool swapped = (bn < 16);        // Q and K segments

  f32x4 acc[4][2];
  for (int i = 0; i < 4; i++)
    for (int j = 0; j < 2; j++) acc[i][j] = (f32x4)0.f;

  const int srow = tid >> 3;                     // 0..63
  const int scol = (tid & 7) * 8;
  const int scolsw = scol ^ ((srow & 7) * 8);    // pre-swizzled source col
  const __bf16* Abase = A + (size_t)(bm * 128) * CD;
  const __bf16* Bbase = BT + (size_t)(bn * 128) * CD;

  const int swz = (l15 & 7) * 8;                  // read-side swizzle
  for (int k0 = 0; k0 < CD; k0 += 64) {
    __syncthreads();
    for (int p = 0; p < 2; p++) {
      int row = p * 64 + srow;
      // wave-uniform LDS dest: rows w*8..w*8+7 of half p (lane adds 16B)
      glds16(Abase + (size_t)row * CD + k0 + scolsw,
             (char*)As + (p * 64 + w * 8) * 128);
      glds16(Bbase + (size_t)row * CD + k0 + scolsw,
             (char*)Bs + (p * 64 + w * 8) * 128);
    }
    __syncthreads();
    for (int kc = 0; kc < 2; kc++) {
      const int koff = (kc * 32 + quad * 8) ^ swz;
      bf16x8 af[4], bfr[2];
      for (int mt = 0; mt < 4; mt++)
        af[mt] = *(const bf16x8*)(As + (wm * 64 + mt * 16 + l15) * 64 + koff);
      for (int nt = 0; nt < 2; nt++)
        bfr[nt] = *(const bf16x8*)(Bs + (wn * 32 + nt * 16 + l15) * 64 + koff);
      if (swapped) {
        for (int mt = 0; mt < 4; mt++)
          for (int nt = 0; nt < 2; nt++)
            acc[mt][nt] = __builtin_amdgcn_mfma_f32_16x16x32_bf16(
                bfr[nt], af[mt], acc[mt][nt], 0, 0, 0);
      } else {
        for (int mt = 0; mt < 4; mt++)
          for (int nt = 0; nt < 2; nt++)
            acc[mt][nt] = __builtin_amdgcn_mfma_f32_16x16x32_bf16(
                af[mt], bfr[nt], acc[mt][nt], 0, 0, 0);
      }
    }
  }

  if (swapped) {
    // C^T frags: reg r -> channel, l15 -> token. 8B stores.
    const int bq_ = bm >> 4;                   // batch (uniform)
    const int tokb = (bm & 15) * 128 + wm * 64;
    __bf16* dst = (bn < 8) ? Qb : Kb;
    const float sc = (bn < 8) ? Q_SCALE : 1.f;
    for (int nt = 0; nt < 2; nt++) {
      const int colb = wn * 32 + nt * 16 + quad * 4;   // 0..127 in block
      const int hq = (bn & 7) * 2 + (colb >> 6);       // head (uniform/lane-row)
      const int d0 = colb & 63;
      bf16x4 bv4 = *(const bf16x4*)(bias + bn * 128 + colb);
      for (int mt = 0; mt < 4; mt++) {
        int tok = tokb + mt * 16 + l15;
        bf16x4 o;
        for (int r = 0; r < 4; r++)
          o[r] = (__bf16)((acc[mt][nt][r] + (float)bv4[r]) * sc);
        *(bf16x4*)(dst + ((size_t)(bq_ * NH + hq) * T_SZ + tok) * HD + d0) = o;
      }
    }
  } else {
    // V: normal frags (reg r -> token), store V^T [B*H, 64, T] 8B along tok
    for (int nt = 0; nt < 2; nt++) {
      int col = bn * 128 + wn * 32 + nt * 16 + l15;
      int c = col & 1023, h = c >> 6, d = c & 63;
      float bv = (float)bias[col];
      for (int mt = 0; mt < 4; mt++) {
        int row0 = bm * 128 + wm * 64 + mt * 16 + quad * 4;
        int b = row0 >> 11, tok0 = row0 & 2047;
        bf16x4 o;
        for (int r = 0; r < 4; r++) o[r] = (__bf16)(acc[mt][nt][r] + bv);
        *(bf16x4*)(Vt + ((size_t)((b << 4) + h) * HD + d) * T_SZ + tok0) = o;
      }
    }
  }
}

// ---------------------------------------------------------------------------
// Out-proj GEMM: d_out[8192,1024] = Yb @ WoT^T + bo, output dtype per flag.
// Same 512-thread 8-wave structure as gemm_qkv; swapped MFMA epilogue.
// ---------------------------------------------------------------------------
__global__ __launch_bounds__(512) void gemm_out(
    const __bf16* __restrict__ A, const __bf16* __restrict__ BT,
    const __bf16* __restrict__ bias, void* __restrict__ Out,
    const int* __restrict__ flag) {
  __shared__ __align__(16) __bf16 As[128 * 64];
  __shared__ __align__(16) __bf16 Bs[128 * 64];
  const int tid = threadIdx.x;
  const int w = tid >> 6, lane = tid & 63;
  const int l15 = lane & 15, quad = lane >> 4;
  const int wm = w & 1, wn = w >> 1;
  const int bm = blockIdx.y, bn = blockIdx.x;

  f32x4 acc[4][2];
  for (int i = 0; i < 4; i++)
    for (int j = 0; j < 2; j++) acc[i][j] = (f32x4)0.f;

  const int srow = tid >> 3;
  const int scol = (tid & 7) * 8;
  const int scolsw = scol ^ ((srow & 7) * 8);
  const __bf16* Abase = A + (size_t)(bm * 128) * CD;
  const __bf16* Bbase = BT + (size_t)(bn * 128) * CD;

  const int swz = (l15 & 7) * 8;
  for (int k0 = 0; k0 < CD; k0 += 64) {
    __syncthreads();
    for (int p = 0; p < 2; p++) {
      int row = p * 64 + srow;
      glds16(Abase + (size_t)row * CD + k0 + scolsw,
             (char*)As + (p * 64 + w * 8) * 128);
      glds16(Bbase + (size_t)row * CD + k0 + scolsw,
             (char*)Bs + (p * 64 + w * 8) * 128);
    }
    __syncthreads();
    for (int kc = 0; kc < 2; kc++) {
      const int koff = (kc * 32 + quad * 8) ^ swz;
      bf16x8 af[4], bfr[2];
      for (int mt = 0; mt < 4; mt++)
        af[mt] = *(const bf16x8*)(As + (wm * 64 + mt * 16 + l15) * 64 + koff);
      for (int nt = 0; nt < 2; nt++)
        bfr[nt] = *(const bf16x8*)(Bs + (wn * 32 + nt * 16 + l15) * 64 + koff);
      for (int mt = 0; mt < 4; mt++)
        for (int nt = 0; nt < 2; nt++)
          acc[mt][nt] = __builtin_amdgcn_mfma_f32_16x16x32_bf16(
              bfr[nt], af[mt], acc[mt][nt], 0, 0, 0);
    }
  }

  const int isbf = flag[0];
  for (int nt = 0; nt < 2; nt++) {
    const int colb = bn * 128 + wn * 32 + nt * 16 + quad * 4;
    bf16x4 bv4 = *(const bf16x4*)(bias + colb);
    for (int mt = 0; mt < 4; mt++) {
      int row = bm * 128 + wm * 64 + mt * 16 + l15;
      if (isbf) {
        bf16x4 o;
        for (int r = 0; r < 4; r++)
          o[r] = (__bf16)(acc[mt][nt][r] + (float)bv4[r]);
        *(bf16x4*)((__bf16*)Out + (size_t)row * CD + colb) = o;
      } else {
        f32x4 o;
        for (int r = 0; r < 4; r++) o[r] = acc[mt][nt][r] + (float)bv4[r];
        *(f32x4*)((float*)Out + (size_t)row * CD + colb) = o;
      }
    }
  }
}

// ---------------------------------------------------------------------------
// Flash attention, causal, transposed-S. Q pre-scaled by 0.125*log2e.
// (unchanged from Round 7/9 — passed)
// ---------------------------------------------------------------------------
__global__ __launch_bounds__(512, 4) void attn(
    const __bf16* __restrict__ Q, const __bf16* __restrict__ K,
    const __bf16* __restrict__ Vt, __bf16* __restrict__ Y) {
  __shared__ __align__(16) __bf16 Ks[2][128 * 64];   // swizzled, 16KB each
  __shared__ __align__(16) __bf16 Vs[2][64 * 140];   // [d][key], pitch 140

  const int tid = threadIdx.x, w = tid >> 6, lane = tid & 63;
  const int l15 = lane & 15, quad = lane >> 4;
  const int lid = blockIdx.x + 8 * blockIdx.y;   // gridDim.x == 8
  const int bh = lid & 63;                       // XCD = lid%8 = bh%8
  const int pairi = lid >> 6;                    // 0..7

  const __bf16* Qbh = Q + (size_t)bh * T_SZ * HD;
  const __bf16* Kbh = K + (size_t)bh * T_SZ * HD;
  const __bf16* Vbh = Vt + (size_t)bh * HD * T_SZ;

  const int srow = tid >> 3;          // 0..63
  const int scol = (tid & 7) * 8;     // 0..56
  const int ksrc = scol ^ ((srow & 7) * 8);   // pre-swizzled source column
  const int b = bh >> 4, h = bh & 15;

  bf16x4 ones;
  for (int r = 0; r < 4; r++) ones[r] = (__bf16)1.0f;

  for (int ph = 0; ph < 2; ph++) {
    const int tq = ph ? (15 - pairi) : pairi;
    const int q0 = tq * 128;
    const int niter = tq + 1;
    const int qw = q0 + w * 16;       // wave's first q row

    __syncthreads();   // prior phase fully done with LDS
    // prologue: stage KV tile 0 into buffer 0 (K async, V via regs)
    glds16(Kbh + (size_t)srow * HD + ksrc, (char*)Ks[0] + w * 1024);
    glds16(Kbh + (size_t)(64 + srow) * HD + ksrc,
           (char*)Ks[0] + 8192 + w * 1024);
    {
      bf16x8 va = *(const bf16x8*)(Vbh + (size_t)srow * T_SZ + scol);
      bf16x8 vb = *(const bf16x8*)(Vbh + (size_t)srow * T_SZ + 64 + scol);
      *(bf16x4*)(Vs[0] + srow * 140 + scol)          = ((bf16x4*)&va)[0];
      *(bf16x4*)(Vs[0] + srow * 140 + scol + 4)      = ((bf16x4*)&va)[1];
      *(bf16x4*)(Vs[0] + srow * 140 + 64 + scol)     = ((bf16x4*)&vb)[0];
      *(bf16x4*)(Vs[0] + srow * 140 + 64 + scol + 4) = ((bf16x4*)&vb)[1];
    }

    // Q fragments (B-operand: n=l15->q, k=quad*8+j->d)
    bf16x8 aq[2];
    for (int kc = 0; kc < 2; kc++)
      aq[kc] = *(const bf16x8*)(
          Qbh + (size_t)(qw + l15) * HD + kc * 32 + quad * 8);

    f32x4 acco[4];   // O^T tiles [d16 x q16]: row d=quad*4+r, col q=l15
    for (int dt = 0; dt < 4; dt++) acco[dt] = (f32x4)0.f;
    f32x4 accl = (f32x4)0.f;   // ones-row MFMA: accl[0] = sum_k P[k][q=l15]
    float m_ = NEG_BIG;

    for (int it = 0; it < niter; it++) {
      const int cur = it & 1;
      const int kv0 = it * 128;
      __syncthreads();   // staging for cur drained (syncthreads waits vmcnt)

      // issue async staging of next K tile + reg-prefetch next V tile
      bf16x8 vna, vnb;
      const bool havenext = (it + 1 < niter);
      if (havenext) {
        int kv1 = kv0 + 128;
        glds16(Kbh + (size_t)(kv1 + srow) * HD + ksrc,
               (char*)Ks[cur ^ 1] + w * 1024);
        glds16(Kbh + (size_t)(kv1 + 64 + srow) * HD + ksrc,
               (char*)Ks[cur ^ 1] + 8192 + w * 1024);
        vna = *(const bf16x8*)(Vbh + (size_t)srow * T_SZ + kv1 + scol);
        vnb = *(const bf16x8*)(Vbh + (size_t)srow * T_SZ + kv1 + 64 + scol);
      }

      // waves whose 16 q rows are entirely below this KV tile skip compute
      if (kv0 <= qw + 15) {
        const __bf16* Ksc = Ks[cur];
        const __bf16* Vsc = Vs[cur];

        // S^T = K Q^T : tiles [key16 x q16]; row key=quad*4+r, col q=l15
        f32x4 accs[8];
        for (int nt = 0; nt < 8; nt++) accs[nt] = (f32x4)0.f;
        const int swz = (l15 & 7) * 8;     // K read swizzle (row&7 == l15&7)
        for (int kc = 0; kc < 2; kc++)
          for (int nt = 0; nt < 8; nt++) {
            bf16x8 ak = *(const bf16x8*)(
                Ksc + (nt * 16 + l15) * 64 + ((kc * 32 + quad * 8) ^ swz));
            accs[nt] = __builtin_amdgcn_mfma_f32_16x16x32_bf16(
                ak, aq[kc], accs[nt], 0, 0, 0);
          }

        // causal mask (only the diagonal tile: kv0 == q0)
        if (kv0 + 127 > qw) {
          int qg = qw + l15;
          for (int nt = 0; nt < 8; nt++) {
            int kg0 = kv0 + nt * 16 + quad * 4;
            for (int r = 0; r < 4; r++)
              if (kg0 + r > qg) accs[nt][r] = NEG_BIG;
          }
        }

        // local max: per-tile max4 then tree + cross-quad shfl_xor
        float tm[8];
        for (int nt = 0; nt < 8; nt++)
          tm[nt] = fmaxf(fmaxf(accs[nt][0], accs[nt][1]),
                         fmaxf(accs[nt][2], accs[nt][3]));
        float u0 = fmaxf(fmaxf(tm[0], tm[1]), fmaxf(tm[2], tm[3]));
        float u1 = fmaxf(fmaxf(tm[4], tm[5]), fmaxf(tm[6], tm[7]));
        float mloc = fmaxf(u0, u1);
        mloc = fmaxf(mloc, __shfl_xor(mloc, 16));
        mloc = fmaxf(mloc, __shfl_xor(mloc, 32));

        // exact skip: if no lane's max grew, alpha==1 -> rescale is a no-op
        if (!__all(mloc <= m_)) {
          float mnew = fmaxf(m_, mloc);
          float alpha = __builtin_amdgcn_exp2f(m_ - mnew);
          m_ = mnew;
          accl[0] *= alpha;
          for (int dt = 0; dt < 4; dt++)
            for (int r = 0; r < 4; r++) acco[dt][r] *= alpha;
        }

        // P^T = exp2(S^T - m): stays in regs as x16 B-operand fragments
        bf16x4 pf[8];
        for (int nt = 0; nt < 8; nt++)
          for (int r = 0; r < 4; r++)
            pf[nt][r] = (__bf16)__builtin_amdgcn_exp2f(accs[nt][r] - m_);

        // O^T += V^T P^T; l-row via ones-A MFMA (dt==4 virtual tile)
#pragma unroll
        for (int nt = 0; nt < 8; nt++) {
          accl = __builtin_amdgcn_mfma_f32_16x16x16bf16_1k(
              *(const s16x4*)&ones, *(const s16x4*)&pf[nt], accl, 0, 0, 0);
#pragma unroll
          for (int dt = 0; dt < 4; dt++) {
            bf16x4 av = *(const bf16x4*)(
                Vsc + (dt * 16 + l15) * 140 + nt * 16 + quad * 4);
            acco[dt] = __builtin_amdgcn_mfma_f32_16x16x16bf16_1k(
                *(const s16x4*)&av, *(const s16x4*)&pf[nt], acco[dt], 0, 0, 0);
          }
        }
      }

      // stage prefetched V tile into the other buffer (iter end; the
      // vmcnt wait here also covers the K glds16 issued at iter start)
      if (havenext) {
        int nb = cur ^ 1;
        *(bf16x4*)(Vs[nb] + srow * 140 + scol)          = ((bf16x4*)&vna)[0];
        *(bf16x4*)(Vs[nb] + srow * 140 + scol + 4)      = ((bf16x4*)&vna)[1];
        *(bf16x4*)(Vs[nb] + srow * 140 + 64 + scol)     = ((bf16x4*)&vnb)[0];
        *(bf16x4*)(Vs[nb] + srow * 140 + 64 + scol + 4) = ((bf16x4*)&vnb)[1];
      }
    }

    // epilogue: O^T -> Y [B*T, 1024], 8B stores (4 consecutive d)
    {
      float rcp = 1.f / accl[0];
      int qg = qw + l15;
      size_t base = ((size_t)(b * T_SZ + qg)) * CD + h * HD + quad * 4;
      for (int dt = 0; dt < 4; dt++) {
        bf16x4 o;
        for (int r = 0; r < 4; r++) o[r] = (__bf16)(acco[dt][r] * rcp);
        *(bf16x4*)(Y + base + dt * 16) = o;
      }
    }
  }
}

// ---------------------------------------------------------------------------
extern "C" void kernel_launch(void* const* d_in, const int* in_sizes, int n_in,
                              void* d_out, int out_size, void* d_ws, size_t ws_size,
                              hipStream_t stream) {
  (void)in_sizes; (void)n_in; (void)out_size; (void)ws_size;
  const void* x  = d_in[0];
  const void* Wq = d_in[2];
  const void* bq = d_in[3];
  const void* Wk = d_in[4];
  const void* bk = d_in[5];
  const void* Wv = d_in[6];
  const void* bv = d_in[7];
  const void* Wo = d_in[8];
  const void* bo = d_in[9];

  char* ws = (char*)d_ws;
  const size_t MB = 1024 * 1024;
  __bf16* WqkvT = (__bf16*)(ws + 0 * MB);          // [3072, 1024]
  __bf16* WoT   = (__bf16*)(ws + 6 * MB);
  __bf16* bqkvc = (__bf16*)(ws + 8 * MB);          // [3072]
  __bf16* boc   = (__bf16*)(ws + 8 * MB + 8192);
  int*    flag  = (int*)   (ws + 8 * MB + 65536);
  __bf16* xc    = (__bf16*)(ws + 9 * MB);          // [8192,1024]; reused as Yb
  __bf16* Qb    = (__bf16*)(ws + 25 * MB);         // [B*H,T,64] pre-scaled
  __bf16* Kb    = (__bf16*)(ws + 41 * MB);
  __bf16* Vt_g  = (__bf16*)(ws + 57 * MB);         // [B*H,64,T]
  __bf16* Yb    = xc;                              // xc dead after QKV GEMM

  dim3 tb(256);
  detect_dtype<<<1, tb, 0, stream>>>((const uint32_t*)x, flag);

  conv_in<<<4096, tb, 0, stream>>>(x, flag, xc, MROWS * CD / 8);
  Ptr4 pb = {{bq, bk, bv, bo}, {bqkvc, bqkvc + CD, bqkvc + 2 * CD, boc}};
  conv_b4<<<4, tb, 0, stream>>>(pb, flag);
  Ptr4 pw = {{Wq, Wk, Wv, Wo},
             {WqkvT, WqkvT + (size_t)CD * CD, WqkvT + 2 * (size_t)CD * CD, WoT}};
  transpose_conv4<<<dim3(16, 16, 4), tb, 0, stream>>>(pw, flag);

  gemm_qkv<<<dim3(24, MROWS / 128), dim3(512), 0, stream>>>(xc, WqkvT, bqkvc,
                                                            Qb, Kb, Vt_g);

  attn<<<dim3(8, B_SZ * NH), dim3(512), 0, stream>>>(Qb, Kb, Vt_g, Yb);

  gemm_out<<<dim3(CD / 128, MROWS / 128), dim3(512), 0, stream>>>(Yb, WoT, boc,
                                                                  d_out, flag);
}

// Round 14
// 266.987 us; speedup vs baseline: 1.4267x; 1.0401x over previous
//
#include <hip/hip_runtime.h>
#include <cstdint>
#include <cstddef>

#define B_SZ 4
#define T_SZ 2048
#define NH 16
#define HD 64
#define CD 1024
#define MROWS (B_SZ*T_SZ)
#define NEG_BIG (-1e30f)
// 0.125 (1/sqrt(64)) * log2(e): fold softmax base-2 conversion into Q prescale
#define Q_SCALE 0.180336880f

typedef __bf16 bf16x8 __attribute__((ext_vector_type(8)));
typedef __bf16 bf16x4 __attribute__((ext_vector_type(4)));
typedef short s16x4 __attribute__((ext_vector_type(4)));
typedef float f32x4 __attribute__((ext_vector_type(4)));

typedef __attribute__((address_space(3))) void* as3p;
typedef const __attribute__((address_space(1))) void* as1p;

__device__ __forceinline__ void glds16(const void* g, void* l) {
  __builtin_amdgcn_global_load_lds((as1p)g, (as3p)l, 16, 0, 0);
}

__device__ __forceinline__ bf16x8 cvt8(const void* src, int isbf, size_t i8) {
  bf16x8 o;
  if (isbf) {
    o = ((const bf16x8*)src)[i8];
  } else {
    const float4* s = (const float4*)((const float*)src + i8 * 8);
    float4 a = s[0], b = s[1];
    o[0] = (__bf16)a.x; o[1] = (__bf16)a.y; o[2] = (__bf16)a.z; o[3] = (__bf16)a.w;
    o[4] = (__bf16)b.x; o[5] = (__bf16)b.y; o[6] = (__bf16)b.z; o[7] = (__bf16)b.w;
  }
  return o;
}

struct Ptr4 { const void* s[4]; __bf16* d[4]; };

// ---------------------------------------------------------------------------
// Fused prep: dtype-detect + x conversion + bias conversion + 4x weight
// transpose-convert, ONE kernel (was 4 serialized dispatches; the persistent
// ~90us gap between sum-of-kernels and total suggests dispatch overhead).
// Every block re-derives the dtype flag from x's first 4KB (L2-hot,
// deterministic); block 0 also publishes it for gemm_out.
// blocks 0-4095: conv_in; 4096-4099: bias conv; 4100-5123: transpose(16,16,4).
// ---------------------------------------------------------------------------
__global__ __launch_bounds__(256) void prep(const void* __restrict__ x,
                                            int* __restrict__ flag,
                                            __bf16* __restrict__ xc,
                                            Ptr4 pw, Ptr4 pb) {
  __shared__ int cnt[256];
  const int t = threadIdx.x;
  {
    const uint32_t* xw = (const uint32_t*)x;
    int c = 0;
    for (int i = 0; i < 4; i++) {
      uint32_t wv = xw[t * 4 + i];
      uint32_t e = (wv >> 7) & 0xFF;
      c += (e >= 100 && e <= 140) ? 1 : 0;
    }
    cnt[t] = c;
    __syncthreads();
    for (int s = 128; s > 0; s >>= 1) {
      if (t < s) cnt[t] += cnt[t + s];
      __syncthreads();
    }
  }
  const int isbf = (cnt[0] > 700) ? 1 : 0;
  const int bid = blockIdx.x;
  if (bid == 0 && t == 0) flag[0] = isbf;

  if (bid < 4096) {
    // conv_in: x -> xc (bf16 canonical), 16B/thread
    int i = bid * 256 + t;                       // grid sized exactly
    ((bf16x8*)xc)[i] = cvt8(x, isbf, i);
  } else if (bid < 4100) {
    // bias conversion (4 vectors of CD)
    int which = bid - 4096;
    if (t < CD / 8)
      ((bf16x8*)pb.d[which])[t] = cvt8(pb.s[which], isbf, t);
  } else {
    // weight transpose-convert: 1024 blocks = (16 c0) x (16 r0) x (4 z)
    __shared__ __align__(16) __bf16 tile[64 * 72];
    int bid2 = bid - 4100;
    const void* W = pw.s[bid2 >> 8];
    __bf16* WT = pw.d[bid2 >> 8];
    const int r0 = ((bid2 >> 4) & 15) * 64, c0 = (bid2 & 15) * 64;
    const int rr = t >> 3, c8 = (t & 7) * 8;
    for (int pp = 0; pp < 2; pp++) {
      int r = pp * 32 + rr;
      *(bf16x8*)(tile + r * 72 + c8) =
          cvt8(W, isbf, ((size_t)(r0 + r) * CD + c0 + c8) / 8);
    }
    __syncthreads();
    for (int pp = 0; pp < 2; pp++) {
      int cc = pp * 32 + rr;
      bf16x8 o;
      for (int j = 0; j < 8; j++) o[j] = tile[(c8 + j) * 72 + cc];
      *(bf16x8*)(WT + (size_t)(c0 + cc) * CD + r0 + c8) = o;
    }
  }
}

// ---------------------------------------------------------------------------
// Fused QKV GEMM: C[8192, 3072] = x @ [WqT;WkT;WvT]^T + bias.
// bn 0-7 -> Q, 8-15 -> K, 16-23 -> V (seg uniform per block).
// 512 threads / 8 waves (2M x 4N), wave tile 64x32: acc[4][2] = 32 AGPR
// -> natural regs/wave ~<=128 -> 2 blocks/CU = 4 waves/SIMD (2x R9).
// NO launch-bounds reg cap (R11: capping below natural usage spills).
// R9 loop structure (single 32KB buffer, 2 barriers/K-step; R10 showed
// dbuf=neutral, XCD-swizzle=worse). XOR-swizzled LDS via pre-swizzled
// global source; reads XOR (l15&7)*8. Q/K swapped MFMA -> bf16x4 stores.
// (unchanged from R12 — passed)
// ---------------------------------------------------------------------------
__global__ __launch_bounds__(512) void gemm_qkv(
    const __bf16* __restrict__ A, const __bf16* __restrict__ BT,
    const __bf16* __restrict__ bias,
    __bf16* __restrict__ Qb, __bf16* __restrict__ Kb, __bf16* __restrict__ Vt) {
  __shared__ __align__(16) __bf16 As[128 * 64];
  __shared__ __align__(16) __bf16 Bs[128 * 64];
  const int tid = threadIdx.x;
  const int w = tid >> 6, lane = tid & 63;
  const int l15 = lane & 15, quad = lane >> 4;
  const int wm = w & 1, wn = w >> 1;             // wn 0..3
  const int bm = blockIdx.y, bn = blockIdx.x;
  const bool swapped = (bn < 16);        // Q and K segments

  f32x4 acc[4][2];
  for (int i = 0; i < 4; i++)
    for (int j = 0; j < 2; j++) acc[i][j] = (f32x4)0.f;

  const int srow = tid >> 3;                     // 0..63
  const int scol = (tid & 7) * 8;
  const int scolsw = scol ^ ((srow & 7) * 8);    // pre-swizzled source col
  const __bf16* Abase = A + (size_t)(bm * 128) * CD;
  const __bf16* Bbase = BT + (size_t)(bn * 128) * CD;

  const int swz = (l15 & 7) * 8;                  // read-side swizzle
  for (int k0 = 0; k0 < CD; k0 += 64) {
    __syncthreads();
    for (int p = 0; p < 2; p++) {
      int row = p * 64 + srow;
      // wave-uniform LDS dest: rows w*8..w*8+7 of half p (lane adds 16B)
      glds16(Abase + (size_t)row * CD + k0 + scolsw,
             (char*)As + (p * 64 + w * 8) * 128);
      glds16(Bbase + (size_t)row * CD + k0 + scolsw,
             (char*)Bs + (p * 64 + w * 8) * 128);
    }
    __syncthreads();
    for (int kc = 0; kc < 2; kc++) {
      const int koff = (kc * 32 + quad * 8) ^ swz;
      bf16x8 af[4], bfr[2];
      for (int mt = 0; mt < 4; mt++)
        af[mt] = *(const bf16x8*)(As + (wm * 64 + mt * 16 + l15) * 64 + koff);
      for (int nt = 0; nt < 2; nt++)
        bfr[nt] = *(const bf16x8*)(Bs + (wn * 32 + nt * 16 + l15) * 64 + koff);
      if (swapped) {
        for (int mt = 0; mt < 4; mt++)
          for (int nt = 0; nt < 2; nt++)
            acc[mt][nt] = __builtin_amdgcn_mfma_f32_16x16x32_bf16(
                bfr[nt], af[mt], acc[mt][nt], 0, 0, 0);
      } else {
        for (int mt = 0; mt < 4; mt++)
          for (int nt = 0; nt < 2; nt++)
            acc[mt][nt] = __builtin_amdgcn_mfma_f32_16x16x32_bf16(
                af[mt], bfr[nt], acc[mt][nt], 0, 0, 0);
      }
    }
  }

  if (swapped) {
    // C^T frags: reg r -> channel, l15 -> token. 8B stores.
    const int bq_ = bm >> 4;                   // batch (uniform)
    const int tokb = (bm & 15) * 128 + wm * 64;
    __bf16* dst = (bn < 8) ? Qb : Kb;
    const float sc = (bn < 8) ? Q_SCALE : 1.f;
    for (int nt = 0; nt < 2; nt++) {
      const int colb = wn * 32 + nt * 16 + quad * 4;   // 0..127 in block
      const int hq = (bn & 7) * 2 + (colb >> 6);       // head
      const int d0 = colb & 63;
      bf16x4 bv4 = *(const bf16x4*)(bias + bn * 128 + colb);
      for (int mt = 0; mt < 4; mt++) {
        int tok = tokb + mt * 16 + l15;
        bf16x4 o;
        for (int r = 0; r < 4; r++)
          o[r] = (__bf16)((acc[mt][nt][r] + (float)bv4[r]) * sc);
        *(bf16x4*)(dst + ((size_t)(bq_ * NH + hq) * T_SZ + tok) * HD + d0) = o;
      }
    }
  } else {
    // V: normal frags (reg r -> token), store V^T [B*H, 64, T] 8B along tok
    for (int nt = 0; nt < 2; nt++) {
      int col = bn * 128 + wn * 32 + nt * 16 + l15;
      int c = col & 1023, h = c >> 6, d = c & 63;
      float bv = (float)bias[col];
      for (int mt = 0; mt < 4; mt++) {
        int row0 = bm * 128 + wm * 64 + mt * 16 + quad * 4;
        int b = row0 >> 11, tok0 = row0 & 2047;
        bf16x4 o;
        for (int r = 0; r < 4; r++) o[r] = (__bf16)(acc[mt][nt][r] + bv);
        *(bf16x4*)(Vt + ((size_t)((b << 4) + h) * HD + d) * T_SZ + tok0) = o;
      }
    }
  }
}

// ---------------------------------------------------------------------------
// Out-proj GEMM: d_out[8192,1024] = Yb @ WoT^T + bo, output dtype per flag.
// Same 512-thread 8-wave structure as gemm_qkv. (unchanged from R12)
// ---------------------------------------------------------------------------
__global__ __launch_bounds__(512) void gemm_out(
    const __bf16* __restrict__ A, const __bf16* __restrict__ BT,
    const __bf16* __restrict__ bias, void* __restrict__ Out,
    const int* __restrict__ flag) {
  __shared__ __align__(16) __bf16 As[128 * 64];
  __shared__ __align__(16) __bf16 Bs[128 * 64];
  const int tid = threadIdx.x;
  const int w = tid >> 6, lane = tid & 63;
  const int l15 = lane & 15, quad = lane >> 4;
  const int wm = w & 1, wn = w >> 1;
  const int bm = blockIdx.y, bn = blockIdx.x;

  f32x4 acc[4][2];
  for (int i = 0; i < 4; i++)
    for (int j = 0; j < 2; j++) acc[i][j] = (f32x4)0.f;

  const int srow = tid >> 3;
  const int scol = (tid & 7) * 8;
  const int scolsw = scol ^ ((srow & 7) * 8);
  const __bf16* Abase = A + (size_t)(bm * 128) * CD;
  const __bf16* Bbase = BT + (size_t)(bn * 128) * CD;

  const int swz = (l15 & 7) * 8;
  for (int k0 = 0; k0 < CD; k0 += 64) {
    __syncthreads();
    for (int p = 0; p < 2; p++) {
      int row = p * 64 + srow;
      glds16(Abase + (size_t)row * CD + k0 + scolsw,
             (char*)As + (p * 64 + w * 8) * 128);
      glds16(Bbase + (size_t)row * CD + k0 + scolsw,
             (char*)Bs + (p * 64 + w * 8) * 128);
    }
    __syncthreads();
    for (int kc = 0; kc < 2; kc++) {
      const int koff = (kc * 32 + quad * 8) ^ swz;
      bf16x8 af[4], bfr[2];
      for (int mt = 0; mt < 4; mt++)
        af[mt] = *(const bf16x8*)(As + (wm * 64 + mt * 16 + l15) * 64 + koff);
      for (int nt = 0; nt < 2; nt++)
        bfr[nt] = *(const bf16x8*)(Bs + (wn * 32 + nt * 16 + l15) * 64 + koff);
      for (int mt = 0; mt < 4; mt++)
        for (int nt = 0; nt < 2; nt++)
          acc[mt][nt] = __builtin_amdgcn_mfma_f32_16x16x32_bf16(
              bfr[nt], af[mt], acc[mt][nt], 0, 0, 0);
    }
  }

  const int isbf = flag[0];
  for (int nt = 0; nt < 2; nt++) {
    const int colb = bn * 128 + wn * 32 + nt * 16 + quad * 4;
    bf16x4 bv4 = *(const bf16x4*)(bias + colb);
    for (int mt = 0; mt < 4; mt++) {
      int row = bm * 128 + wm * 64 + mt * 16 + l15;
      if (isbf) {
        bf16x4 o;
        for (int r = 0; r < 4; r++)
          o[r] = (__bf16)(acc[mt][nt][r] + (float)bv4[r]);
        *(bf16x4*)((__bf16*)Out + (size_t)row * CD + colb) = o;
      } else {
        f32x4 o;
        for (int r = 0; r < 4; r++) o[r] = acc[mt][nt][r] + (float)bv4[r];
        *(f32x4*)((float*)Out + (size_t)row * CD + colb) = o;
      }
    }
  }
}

// ---------------------------------------------------------------------------
// Flash attention, causal, transposed-S. Q pre-scaled by 0.125*log2e.
// (unchanged from Round 7/9/12 — passed)
// ---------------------------------------------------------------------------
__global__ __launch_bounds__(512, 4) void attn(
    const __bf16* __restrict__ Q, const __bf16* __restrict__ K,
    const __bf16* __restrict__ Vt, __bf16* __restrict__ Y) {
  __shared__ __align__(16) __bf16 Ks[2][128 * 64];   // swizzled, 16KB each
  __shared__ __align__(16) __bf16 Vs[2][64 * 140];   // [d][key], pitch 140

  const int tid = threadIdx.x, w = tid >> 6, lane = tid & 63;
  const int l15 = lane & 15, quad = lane >> 4;
  const int lid = blockIdx.x + 8 * blockIdx.y;   // gridDim.x == 8
  const int bh = lid & 63;                       // XCD = lid%8 = bh%8
  const int pairi = lid >> 6;                    // 0..7

  const __bf16* Qbh = Q + (size_t)bh * T_SZ * HD;
  const __bf16* Kbh = K + (size_t)bh * T_SZ * HD;
  const __bf16* Vbh = Vt + (size_t)bh * HD * T_SZ;

  const int srow = tid >> 3;          // 0..63
  const int scol = (tid & 7) * 8;     // 0..56
  const int ksrc = scol ^ ((srow & 7) * 8);   // pre-swizzled source column
  const int b = bh >> 4, h = bh & 15;

  bf16x4 ones;
  for (int r = 0; r < 4; r++) ones[r] = (__bf16)1.0f;

  for (int ph = 0; ph < 2; ph++) {
    const int tq = ph ? (15 - pairi) : pairi;
    const int q0 = tq * 128;
    const int niter = tq + 1;
    const int qw = q0 + w * 16;       // wave's first q row

    __syncthreads();   // prior phase fully done with LDS
    // prologue: stage KV tile 0 into buffer 0 (K async, V via regs)
    glds16(Kbh + (size_t)srow * HD + ksrc, (char*)Ks[0] + w * 1024);
    glds16(Kbh + (size_t)(64 + srow) * HD + ksrc,
           (char*)Ks[0] + 8192 + w * 1024);
    {
      bf16x8 va = *(const bf16x8*)(Vbh + (size_t)srow * T_SZ + scol);
      bf16x8 vb = *(const bf16x8*)(Vbh + (size_t)srow * T_SZ + 64 + scol);
      *(bf16x4*)(Vs[0] + srow * 140 + scol)          = ((bf16x4*)&va)[0];
      *(bf16x4*)(Vs[0] + srow * 140 + scol + 4)      = ((bf16x4*)&va)[1];
      *(bf16x4*)(Vs[0] + srow * 140 + 64 + scol)     = ((bf16x4*)&vb)[0];
      *(bf16x4*)(Vs[0] + srow * 140 + 64 + scol + 4) = ((bf16x4*)&vb)[1];
    }

    // Q fragments (B-operand: n=l15->q, k=quad*8+j->d)
    bf16x8 aq[2];
    for (int kc = 0; kc < 2; kc++)
      aq[kc] = *(const bf16x8*)(
          Qbh + (size_t)(qw + l15) * HD + kc * 32 + quad * 8);

    f32x4 acco[4];   // O^T tiles [d16 x q16]: row d=quad*4+r, col q=l15
    for (int dt = 0; dt < 4; dt++) acco[dt] = (f32x4)0.f;
    f32x4 accl = (f32x4)0.f;   // ones-row MFMA: accl[0] = sum_k P[k][q=l15]
    float m_ = NEG_BIG;

    for (int it = 0; it < niter; it++) {
      const int cur = it & 1;
      const int kv0 = it * 128;
      __syncthreads();   // staging for cur drained (syncthreads waits vmcnt)

      // issue async staging of next K tile + reg-prefetch next V tile
      bf16x8 vna, vnb;
      const bool havenext = (it + 1 < niter);
      if (havenext) {
        int kv1 = kv0 + 128;
        glds16(Kbh + (size_t)(kv1 + srow) * HD + ksrc,
               (char*)Ks[cur ^ 1] + w * 1024);
        glds16(Kbh + (size_t)(kv1 + 64 + srow) * HD + ksrc,
               (char*)Ks[cur ^ 1] + 8192 + w * 1024);
        vna = *(const bf16x8*)(Vbh + (size_t)srow * T_SZ + kv1 + scol);
        vnb = *(const bf16x8*)(Vbh + (size_t)srow * T_SZ + kv1 + 64 + scol);
      }

      // waves whose 16 q rows are entirely below this KV tile skip compute
      if (kv0 <= qw + 15) {
        const __bf16* Ksc = Ks[cur];
        const __bf16* Vsc = Vs[cur];

        // S^T = K Q^T : tiles [key16 x q16]; row key=quad*4+r, col q=l15
        f32x4 accs[8];
        for (int nt = 0; nt < 8; nt++) accs[nt] = (f32x4)0.f;
        const int swz = (l15 & 7) * 8;     // K read swizzle (row&7 == l15&7)
        for (int kc = 0; kc < 2; kc++)
          for (int nt = 0; nt < 8; nt++) {
            bf16x8 ak = *(const bf16x8*)(
                Ksc + (nt * 16 + l15) * 64 + ((kc * 32 + quad * 8) ^ swz));
            accs[nt] = __builtin_amdgcn_mfma_f32_16x16x32_bf16(
                ak, aq[kc], accs[nt], 0, 0, 0);
          }

        // causal mask (only the diagonal tile: kv0 == q0)
        if (kv0 + 127 > qw) {
          int qg = qw + l15;
          for (int nt = 0; nt < 8; nt++) {
            int kg0 = kv0 + nt * 16 + quad * 4;
            for (int r = 0; r < 4; r++)
              if (kg0 + r > qg) accs[nt][r] = NEG_BIG;
          }
        }

        // local max: per-tile max4 then tree + cross-quad shfl_xor
        float tm[8];
        for (int nt = 0; nt < 8; nt++)
          tm[nt] = fmaxf(fmaxf(accs[nt][0], accs[nt][1]),
                         fmaxf(accs[nt][2], accs[nt][3]));
        float u0 = fmaxf(fmaxf(tm[0], tm[1]), fmaxf(tm[2], tm[3]));
        float u1 = fmaxf(fmaxf(tm[4], tm[5]), fmaxf(tm[6], tm[7]));
        float mloc = fmaxf(u0, u1);
        mloc = fmaxf(mloc, __shfl_xor(mloc, 16));
        mloc = fmaxf(mloc, __shfl_xor(mloc, 32));

        // exact skip: if no lane's max grew, alpha==1 -> rescale is a no-op
        if (!__all(mloc <= m_)) {
          float mnew = fmaxf(m_, mloc);
          float alpha = __builtin_amdgcn_exp2f(m_ - mnew);
          m_ = mnew;
          accl[0] *= alpha;
          for (int dt = 0; dt < 4; dt++)
            for (int r = 0; r < 4; r++) acco[dt][r] *= alpha;
        }

        // P^T = exp2(S^T - m): stays in regs as x16 B-operand fragments
        bf16x4 pf[8];
        for (int nt = 0; nt < 8; nt++)
          for (int r = 0; r < 4; r++)
            pf[nt][r] = (__bf16)__builtin_amdgcn_exp2f(accs[nt][r] - m_);

        // O^T += V^T P^T; l-row via ones-A MFMA (dt==4 virtual tile)
#pragma unroll
        for (int nt = 0; nt < 8; nt++) {
          accl = __builtin_amdgcn_mfma_f32_16x16x16bf16_1k(
              *(const s16x4*)&ones, *(const s16x4*)&pf[nt], accl, 0, 0, 0);
#pragma unroll
          for (int dt = 0; dt < 4; dt++) {
            bf16x4 av = *(const bf16x4*)(
                Vsc + (dt * 16 + l15) * 140 + nt * 16 + quad * 4);
            acco[dt] = __builtin_amdgcn_mfma_f32_16x16x16bf16_1k(
                *(const s16x4*)&av, *(const s16x4*)&pf[nt], acco[dt], 0, 0, 0);
          }
        }
      }

      // stage prefetched V tile into the other buffer (iter end; the
      // vmcnt wait here also covers the K glds16 issued at iter start)
      if (havenext) {
        int nb = cur ^ 1;
        *(bf16x4*)(Vs[nb] + srow * 140 + scol)          = ((bf16x4*)&vna)[0];
        *(bf16x4*)(Vs[nb] + srow * 140 + scol + 4)      = ((bf16x4*)&vna)[1];
        *(bf16x4*)(Vs[nb] + srow * 140 + 64 + scol)     = ((bf16x4*)&vnb)[0];
        *(bf16x4*)(Vs[nb] + srow * 140 + 64 + scol + 4) = ((bf16x4*)&vnb)[1];
      }
    }

    // epilogue: O^T -> Y [B*T, 1024], 8B stores (4 consecutive d)
    {
      float rcp = 1.f / accl[0];
      int qg = qw + l15;
      size_t base = ((size_t)(b * T_SZ + qg)) * CD + h * HD + quad * 4;
      for (int dt = 0; dt < 4; dt++) {
        bf16x4 o;
        for (int r = 0; r < 4; r++) o[r] = (__bf16)(acco[dt][r] * rcp);
        *(bf16x4*)(Y + base + dt * 16) = o;
      }
    }
  }
}

// ---------------------------------------------------------------------------
extern "C" void kernel_launch(void* const* d_in, const int* in_sizes, int n_in,
                              void* d_out, int out_size, void* d_ws, size_t ws_size,
                              hipStream_t stream) {
  (void)in_sizes; (void)n_in; (void)out_size; (void)ws_size;
  const void* x  = d_in[0];
  const void* Wq = d_in[2];
  const void* bq = d_in[3];
  const void* Wk = d_in[4];
  const void* bk = d_in[5];
  const void* Wv = d_in[6];
  const void* bv = d_in[7];
  const void* Wo = d_in[8];
  const void* bo = d_in[9];

  char* ws = (char*)d_ws;
  const size_t MB = 1024 * 1024;
  __bf16* WqkvT = (__bf16*)(ws + 0 * MB);          // [3072, 1024]
  __bf16* WoT   = (__bf16*)(ws + 6 * MB);
  __bf16* bqkvc = (__bf16*)(ws + 8 * MB);          // [3072]
  __bf16* boc   = (__bf16*)(ws + 8 * MB + 8192);
  int*    flag  = (int*)   (ws + 8 * MB + 65536);
  __bf16* xc    = (__bf16*)(ws + 9 * MB);          // [8192,1024]; reused as Yb
  __bf16* Qb    = (__bf16*)(ws + 25 * MB);         // [B*H,T,64] pre-scaled
  __bf16* Kb    = (__bf16*)(ws + 41 * MB);
  __bf16* Vt_g  = (__bf16*)(ws + 57 * MB);         // [B*H,64,T]
  __bf16* Yb    = xc;                              // xc dead after QKV GEMM

  Ptr4 pw = {{Wq, Wk, Wv, Wo},
             {WqkvT, WqkvT + (size_t)CD * CD, WqkvT + 2 * (size_t)CD * CD, WoT}};
  Ptr4 pb = {{bq, bk, bv, bo}, {bqkvc, bqkvc + CD, bqkvc + 2 * CD, boc}};

  prep<<<5124, dim3(256), 0, stream>>>(x, flag, xc, pw, pb);

  gemm_qkv<<<dim3(24, MROWS / 128), dim3(512), 0, stream>>>(xc, WqkvT, bqkvc,
                                                            Qb, Kb, Vt_g);

  attn<<<dim3(8, B_SZ * NH), dim3(512), 0, stream>>>(Qb, Kb, Vt_g, Yb);

  gemm_out<<<dim3(CD / 128, MROWS / 128), dim3(512), 0, stream>>>(Yb, WoT, boc,
                                                                  d_out, flag);
}

// Round 15
// 264.573 us; speedup vs baseline: 1.4397x; 1.0091x over previous
//
#include <hip/hip_runtime.h>
#include <cstdint>
#include <cstddef>

#define B_SZ 4
#define T_SZ 2048
#define NH 16
#define HD 64
#define CD 1024
#define MROWS (B_SZ*T_SZ)
#define NEG_BIG (-1e30f)
// 0.125 (1/sqrt(64)) * log2(e): fold softmax base-2 conversion into Q prescale
#define Q_SCALE 0.180336880f

typedef __bf16 bf16x8 __attribute__((ext_vector_type(8)));
typedef __bf16 bf16x4 __attribute__((ext_vector_type(4)));
typedef short s16x4 __attribute__((ext_vector_type(4)));
typedef float f32x4 __attribute__((ext_vector_type(4)));

typedef __attribute__((address_space(3))) void* as3p;
typedef const __attribute__((address_space(1))) void* as1p;

__device__ __forceinline__ void glds16(const void* g, void* l) {
  __builtin_amdgcn_global_load_lds((as1p)g, (as3p)l, 16, 0, 0);
}

__device__ __forceinline__ bf16x8 cvt8(const void* src, int isbf, size_t i8) {
  bf16x8 o;
  if (isbf) {
    o = ((const bf16x8*)src)[i8];
  } else {
    const float4* s = (const float4*)((const float*)src + i8 * 8);
    float4 a = s[0], b = s[1];
    o[0] = (__bf16)a.x; o[1] = (__bf16)a.y; o[2] = (__bf16)a.z; o[3] = (__bf16)a.w;
    o[4] = (__bf16)b.x; o[5] = (__bf16)b.y; o[6] = (__bf16)b.z; o[7] = (__bf16)b.w;
  }
  return o;
}

struct Ptr4 { const void* s[4]; __bf16* d[4]; };

// ---------------------------------------------------------------------------
// Fused prep: dtype-detect + x conversion + bias conversion + 4x weight
// transpose-convert, ONE kernel. (unchanged from R14 — passed, saved ~11us)
// blocks 0-4095: conv_in; 4096-4099: bias conv; 4100-5123: transpose(16,16,4).
// ---------------------------------------------------------------------------
__global__ __launch_bounds__(256) void prep(const void* __restrict__ x,
                                            int* __restrict__ flag,
                                            __bf16* __restrict__ xc,
                                            Ptr4 pw, Ptr4 pb) {
  __shared__ int cnt[256];
  const int t = threadIdx.x;
  {
    const uint32_t* xw = (const uint32_t*)x;
    int c = 0;
    for (int i = 0; i < 4; i++) {
      uint32_t wv = xw[t * 4 + i];
      uint32_t e = (wv >> 7) & 0xFF;
      c += (e >= 100 && e <= 140) ? 1 : 0;
    }
    cnt[t] = c;
    __syncthreads();
    for (int s = 128; s > 0; s >>= 1) {
      if (t < s) cnt[t] += cnt[t + s];
      __syncthreads();
    }
  }
  const int isbf = (cnt[0] > 700) ? 1 : 0;
  const int bid = blockIdx.x;
  if (bid == 0 && t == 0) flag[0] = isbf;

  if (bid < 4096) {
    int i = bid * 256 + t;
    ((bf16x8*)xc)[i] = cvt8(x, isbf, i);
  } else if (bid < 4100) {
    int which = bid - 4096;
    if (t < CD / 8)
      ((bf16x8*)pb.d[which])[t] = cvt8(pb.s[which], isbf, t);
  } else {
    __shared__ __align__(16) __bf16 tile[64 * 72];
    int bid2 = bid - 4100;
    const void* W = pw.s[bid2 >> 8];
    __bf16* WT = pw.d[bid2 >> 8];
    const int r0 = ((bid2 >> 4) & 15) * 64, c0 = (bid2 & 15) * 64;
    const int rr = t >> 3, c8 = (t & 7) * 8;
    for (int pp = 0; pp < 2; pp++) {
      int r = pp * 32 + rr;
      *(bf16x8*)(tile + r * 72 + c8) =
          cvt8(W, isbf, ((size_t)(r0 + r) * CD + c0 + c8) / 8);
    }
    __syncthreads();
    for (int pp = 0; pp < 2; pp++) {
      int cc = pp * 32 + rr;
      bf16x8 o;
      for (int j = 0; j < 8; j++) o[j] = tile[(c8 + j) * 72 + cc];
      *(bf16x8*)(WT + (size_t)(c0 + cc) * CD + r0 + c8) = o;
    }
  }
}

// ---------------------------------------------------------------------------
// Fused QKV GEMM: C[8192, 3072] = x @ [WqT;WkT;WvT]^T + bias.
// bn 0-7 -> Q, 8-15 -> K, 16-23 -> V (seg uniform per block).
// 512 threads / 8 waves (2M x 4N), wave tile 64x32, acc[4][2]=32 AGPR.
// BK=128 (was 64): SINGLE 64KB buffer, 8 K-steps instead of 16 -> barrier
// drains halve in count (the drain, paid 16x in lockstep, was the 26%-
// MfmaUtil stall; at 660 TF we sat exactly at the guide's 2-phase ceiling).
// LDS 64KB -> still 2 blocks/CU. Staging: srow16=tid>>4, scolE=(tid&15)*8
// -> LDS dest (p*32+w*4)*256 + lane*16 (wave-uniform + lane*16, exact
// glds16 contract). Swizzle: store global col scolE^((row&7)*8); read
// koff^( (l15&7)*8 ) with row&7==l15&7 (mt*16, wm*64 preserve mod 8).
// Q/K swapped MFMA -> bf16x4 epilogue stores. No reg cap (R11 lesson).
// ---------------------------------------------------------------------------
__global__ __launch_bounds__(512) void gemm_qkv(
    const __bf16* __restrict__ A, const __bf16* __restrict__ BT,
    const __bf16* __restrict__ bias,
    __bf16* __restrict__ Qb, __bf16* __restrict__ Kb, __bf16* __restrict__ Vt) {
  __shared__ __align__(16) __bf16 As[128 * 128];
  __shared__ __align__(16) __bf16 Bs[128 * 128];
  const int tid = threadIdx.x;
  const int w = tid >> 6, lane = tid & 63;
  const int l15 = lane & 15, quad = lane >> 4;
  const int wm = w & 1, wn = w >> 1;             // wn 0..3
  const int bm = blockIdx.y, bn = blockIdx.x;
  const bool swapped = (bn < 16);        // Q and K segments

  f32x4 acc[4][2];
  for (int i = 0; i < 4; i++)
    for (int j = 0; j < 2; j++) acc[i][j] = (f32x4)0.f;

  const int srow16 = tid >> 4;                   // 0..31
  const int scolE = (tid & 15) * 8;              // 0..120 elems
  const int scolsw = scolE ^ ((srow16 & 7) * 8); // pre-swizzled source col
  const __bf16* Abase = A + (size_t)(bm * 128) * CD;
  const __bf16* Bbase = BT + (size_t)(bn * 128) * CD;

  const int swz = (l15 & 7) * 8;                  // read-side swizzle
  for (int k0 = 0; k0 < CD; k0 += 128) {
    __syncthreads();
    for (int p = 0; p < 4; p++) {
      int row = p * 32 + srow16;
      glds16(Abase + (size_t)row * CD + k0 + scolsw,
             (char*)As + (p * 32 + w * 4) * 256);
      glds16(Bbase + (size_t)row * CD + k0 + scolsw,
             (char*)Bs + (p * 32 + w * 4) * 256);
    }
    __syncthreads();
    for (int kc = 0; kc < 4; kc++) {
      const int koff = (kc * 32 + quad * 8) ^ swz;
      bf16x8 af[4], bfr[2];
      for (int mt = 0; mt < 4; mt++)
        af[mt] = *(const bf16x8*)(As + (wm * 64 + mt * 16 + l15) * 128 + koff);
      for (int nt = 0; nt < 2; nt++)
        bfr[nt] = *(const bf16x8*)(Bs + (wn * 32 + nt * 16 + l15) * 128 + koff);
      if (swapped) {
        for (int mt = 0; mt < 4; mt++)
          for (int nt = 0; nt < 2; nt++)
            acc[mt][nt] = __builtin_amdgcn_mfma_f32_16x16x32_bf16(
                bfr[nt], af[mt], acc[mt][nt], 0, 0, 0);
      } else {
        for (int mt = 0; mt < 4; mt++)
          for (int nt = 0; nt < 2; nt++)
            acc[mt][nt] = __builtin_amdgcn_mfma_f32_16x16x32_bf16(
                af[mt], bfr[nt], acc[mt][nt], 0, 0, 0);
      }
    }
  }

  if (swapped) {
    // C^T frags: reg r -> channel, l15 -> token. 8B stores.
    const int bq_ = bm >> 4;                   // batch (uniform)
    const int tokb = (bm & 15) * 128 + wm * 64;
    __bf16* dst = (bn < 8) ? Qb : Kb;
    const float sc = (bn < 8) ? Q_SCALE : 1.f;
    for (int nt = 0; nt < 2; nt++) {
      const int colb = wn * 32 + nt * 16 + quad * 4;   // 0..127 in block
      const int hq = (bn & 7) * 2 + (colb >> 6);       // head
      const int d0 = colb & 63;
      bf16x4 bv4 = *(const bf16x4*)(bias + bn * 128 + colb);
      for (int mt = 0; mt < 4; mt++) {
        int tok = tokb + mt * 16 + l15;
        bf16x4 o;
        for (int r = 0; r < 4; r++)
          o[r] = (__bf16)((acc[mt][nt][r] + (float)bv4[r]) * sc);
        *(bf16x4*)(dst + ((size_t)(bq_ * NH + hq) * T_SZ + tok) * HD + d0) = o;
      }
    }
  } else {
    // V: normal frags (reg r -> token), store V^T [B*H, 64, T] 8B along tok
    for (int nt = 0; nt < 2; nt++) {
      int col = bn * 128 + wn * 32 + nt * 16 + l15;
      int c = col & 1023, h = c >> 6, d = c & 63;
      float bv = (float)bias[col];
      for (int mt = 0; mt < 4; mt++) {
        int row0 = bm * 128 + wm * 64 + mt * 16 + quad * 4;
        int b = row0 >> 11, tok0 = row0 & 2047;
        bf16x4 o;
        for (int r = 0; r < 4; r++) o[r] = (__bf16)(acc[mt][nt][r] + bv);
        *(bf16x4*)(Vt + ((size_t)((b << 4) + h) * HD + d) * T_SZ + tok0) = o;
      }
    }
  }
}

// ---------------------------------------------------------------------------
// Out-proj GEMM: d_out[8192,1024] = Yb @ WoT^T + bo, output dtype per flag.
// BK=64 structure kept as-is (control vs gemm_qkv's BK=128 change).
// ---------------------------------------------------------------------------
__global__ __launch_bounds__(512) void gemm_out(
    const __bf16* __restrict__ A, const __bf16* __restrict__ BT,
    const __bf16* __restrict__ bias, void* __restrict__ Out,
    const int* __restrict__ flag) {
  __shared__ __align__(16) __bf16 As[128 * 64];
  __shared__ __align__(16) __bf16 Bs[128 * 64];
  const int tid = threadIdx.x;
  const int w = tid >> 6, lane = tid & 63;
  const int l15 = lane & 15, quad = lane >> 4;
  const int wm = w & 1, wn = w >> 1;
  const int bm = blockIdx.y, bn = blockIdx.x;

  f32x4 acc[4][2];
  for (int i = 0; i < 4; i++)
    for (int j = 0; j < 2; j++) acc[i][j] = (f32x4)0.f;

  const int srow = tid >> 3;
  const int scol = (tid & 7) * 8;
  const int scolsw = scol ^ ((srow & 7) * 8);
  const __bf16* Abase = A + (size_t)(bm * 128) * CD;
  const __bf16* Bbase = BT + (size_t)(bn * 128) * CD;

  const int swz = (l15 & 7) * 8;
  for (int k0 = 0; k0 < CD; k0 += 64) {
    __syncthreads();
    for (int p = 0; p < 2; p++) {
      int row = p * 64 + srow;
      glds16(Abase + (size_t)row * CD + k0 + scolsw,
             (char*)As + (p * 64 + w * 8) * 128);
      glds16(Bbase + (size_t)row * CD + k0 + scolsw,
             (char*)Bs + (p * 64 + w * 8) * 128);
    }
    __syncthreads();
    for (int kc = 0; kc < 2; kc++) {
      const int koff = (kc * 32 + quad * 8) ^ swz;
      bf16x8 af[4], bfr[2];
      for (int mt = 0; mt < 4; mt++)
        af[mt] = *(const bf16x8*)(As + (wm * 64 + mt * 16 + l15) * 64 + koff);
      for (int nt = 0; nt < 2; nt++)
        bfr[nt] = *(const bf16x8*)(Bs + (wn * 32 + nt * 16 + l15) * 64 + koff);
      for (int mt = 0; mt < 4; mt++)
        for (int nt = 0; nt < 2; nt++)
          acc[mt][nt] = __builtin_amdgcn_mfma_f32_16x16x32_bf16(
              bfr[nt], af[mt], acc[mt][nt], 0, 0, 0);
    }
  }

  const int isbf = flag[0];
  for (int nt = 0; nt < 2; nt++) {
    const int colb = bn * 128 + wn * 32 + nt * 16 + quad * 4;
    bf16x4 bv4 = *(const bf16x4*)(bias + colb);
    for (int mt = 0; mt < 4; mt++) {
      int row = bm * 128 + wm * 64 + mt * 16 + l15;
      if (isbf) {
        bf16x4 o;
        for (int r = 0; r < 4; r++)
          o[r] = (__bf16)(acc[mt][nt][r] + (float)bv4[r]);
        *(bf16x4*)((__bf16*)Out + (size_t)row * CD + colb) = o;
      } else {
        f32x4 o;
        for (int r = 0; r < 4; r++) o[r] = acc[mt][nt][r] + (float)bv4[r];
        *(f32x4*)((float*)Out + (size_t)row * CD + colb) = o;
      }
    }
  }
}

// ---------------------------------------------------------------------------
// Flash attention, causal, transposed-S. Q pre-scaled by 0.125*log2e.
// R12 structure + s_setprio(1/0) around the MFMA clusters (guide m191:
// +4-7% on attn, where blocks run phase-independent — unlike lockstep GEMM).
// ---------------------------------------------------------------------------
__global__ __launch_bounds__(512, 4) void attn(
    const __bf16* __restrict__ Q, const __bf16* __restrict__ K,
    const __bf16* __restrict__ Vt, __bf16* __restrict__ Y) {
  __shared__ __align__(16) __bf16 Ks[2][128 * 64];   // swizzled, 16KB each
  __shared__ __align__(16) __bf16 Vs[2][64 * 140];   // [d][key], pitch 140

  const int tid = threadIdx.x, w = tid >> 6, lane = tid & 63;
  const int l15 = lane & 15, quad = lane >> 4;
  const int lid = blockIdx.x + 8 * blockIdx.y;   // gridDim.x == 8
  const int bh = lid & 63;                       // XCD = lid%8 = bh%8
  const int pairi = lid >> 6;                    // 0..7

  const __bf16* Qbh = Q + (size_t)bh * T_SZ * HD;
  const __bf16* Kbh = K + (size_t)bh * T_SZ * HD;
  const __bf16* Vbh = Vt + (size_t)bh * HD * T_SZ;

  const int srow = tid >> 3;          // 0..63
  const int scol = (tid & 7) * 8;     // 0..56
  const int ksrc = scol ^ ((srow & 7) * 8);   // pre-swizzled source column
  const int b = bh >> 4, h = bh & 15;

  bf16x4 ones;
  for (int r = 0; r < 4; r++) ones[r] = (__bf16)1.0f;

  for (int ph = 0; ph < 2; ph++) {
    const int tq = ph ? (15 - pairi) : pairi;
    const int q0 = tq * 128;
    const int niter = tq + 1;
    const int qw = q0 + w * 16;       // wave's first q row

    __syncthreads();   // prior phase fully done with LDS
    // prologue: stage KV tile 0 into buffer 0 (K async, V via regs)
    glds16(Kbh + (size_t)srow * HD + ksrc, (char*)Ks[0] + w * 1024);
    glds16(Kbh + (size_t)(64 + srow) * HD + ksrc,
           (char*)Ks[0] + 8192 + w * 1024);
    {
      bf16x8 va = *(const bf16x8*)(Vbh + (size_t)srow * T_SZ + scol);
      bf16x8 vb = *(const bf16x8*)(Vbh + (size_t)srow * T_SZ + 64 + scol);
      *(bf16x4*)(Vs[0] + srow * 140 + scol)          = ((bf16x4*)&va)[0];
      *(bf16x4*)(Vs[0] + srow * 140 + scol + 4)      = ((bf16x4*)&va)[1];
      *(bf16x4*)(Vs[0] + srow * 140 + 64 + scol)     = ((bf16x4*)&vb)[0];
      *(bf16x4*)(Vs[0] + srow * 140 + 64 + scol + 4) = ((bf16x4*)&vb)[1];
    }

    // Q fragments (B-operand: n=l15->q, k=quad*8+j->d)
    bf16x8 aq[2];
    for (int kc = 0; kc < 2; kc++)
      aq[kc] = *(const bf16x8*)(
          Qbh + (size_t)(qw + l15) * HD + kc * 32 + quad * 8);

    f32x4 acco[4];   // O^T tiles [d16 x q16]: row d=quad*4+r, col q=l15
    for (int dt = 0; dt < 4; dt++) acco[dt] = (f32x4)0.f;
    f32x4 accl = (f32x4)0.f;   // ones-row MFMA: accl[0] = sum_k P[k][q=l15]
    float m_ = NEG_BIG;

    for (int it = 0; it < niter; it++) {
      const int cur = it & 1;
      const int kv0 = it * 128;
      __syncthreads();   // staging for cur drained (syncthreads waits vmcnt)

      // issue async staging of next K tile + reg-prefetch next V tile
      bf16x8 vna, vnb;
      const bool havenext = (it + 1 < niter);
      if (havenext) {
        int kv1 = kv0 + 128;
        glds16(Kbh + (size_t)(kv1 + srow) * HD + ksrc,
               (char*)Ks[cur ^ 1] + w * 1024);
        glds16(Kbh + (size_t)(kv1 + 64 + srow) * HD + ksrc,
               (char*)Ks[cur ^ 1] + 8192 + w * 1024);
        vna = *(const bf16x8*)(Vbh + (size_t)srow * T_SZ + kv1 + scol);
        vnb = *(const bf16x8*)(Vbh + (size_t)srow * T_SZ + kv1 + 64 + scol);
      }

      // waves whose 16 q rows are entirely below this KV tile skip compute
      if (kv0 <= qw + 15) {
        const __bf16* Ksc = Ks[cur];
        const __bf16* Vsc = Vs[cur];

        // S^T = K Q^T : tiles [key16 x q16]; row key=quad*4+r, col q=l15
        f32x4 accs[8];
        for (int nt = 0; nt < 8; nt++) accs[nt] = (f32x4)0.f;
        const int swz = (l15 & 7) * 8;     // K read swizzle (row&7 == l15&7)
        __builtin_amdgcn_s_setprio(1);
        for (int kc = 0; kc < 2; kc++)
          for (int nt = 0; nt < 8; nt++) {
            bf16x8 ak = *(const bf16x8*)(
                Ksc + (nt * 16 + l15) * 64 + ((kc * 32 + quad * 8) ^ swz));
            accs[nt] = __builtin_amdgcn_mfma_f32_16x16x32_bf16(
                ak, aq[kc], accs[nt], 0, 0, 0);
          }
        __builtin_amdgcn_s_setprio(0);

        // causal mask (only the diagonal tile: kv0 == q0)
        if (kv0 + 127 > qw) {
          int qg = qw + l15;
          for (int nt = 0; nt < 8; nt++) {
            int kg0 = kv0 + nt * 16 + quad * 4;
            for (int r = 0; r < 4; r++)
              if (kg0 + r > qg) accs[nt][r] = NEG_BIG;
          }
        }

        // local max: per-tile max4 then tree + cross-quad shfl_xor
        float tm[8];
        for (int nt = 0; nt < 8; nt++)
          tm[nt] = fmaxf(fmaxf(accs[nt][0], accs[nt][1]),
                         fmaxf(accs[nt][2], accs[nt][3]));
        float u0 = fmaxf(fmaxf(tm[0], tm[1]), fmaxf(tm[2], tm[3]));
        float u1 = fmaxf(fmaxf(tm[4], tm[5]), fmaxf(tm[6], tm[7]));
        float mloc = fmaxf(u0, u1);
        mloc = fmaxf(mloc, __shfl_xor(mloc, 16));
        mloc = fmaxf(mloc, __shfl_xor(mloc, 32));

        // exact skip: if no lane's max grew, alpha==1 -> rescale is a no-op
        if (!__all(mloc <= m_)) {
          float mnew = fmaxf(m_, mloc);
          float alpha = __builtin_amdgcn_exp2f(m_ - mnew);
          m_ = mnew;
          accl[0] *= alpha;
          for (int dt = 0; dt < 4; dt++)
            for (int r = 0; r < 4; r++) acco[dt][r] *= alpha;
        }

        // P^T = exp2(S^T - m): stays in regs as x16 B-operand fragments
        bf16x4 pf[8];
        for (int nt = 0; nt < 8; nt++)
          for (int r = 0; r < 4; r++)
            pf[nt][r] = (__bf16)__builtin_amdgcn_exp2f(accs[nt][r] - m_);

        // O^T += V^T P^T; l-row via ones-A MFMA (dt==4 virtual tile)
        __builtin_amdgcn_s_setprio(1);
#pragma unroll
        for (int nt = 0; nt < 8; nt++) {
          accl = __builtin_amdgcn_mfma_f32_16x16x16bf16_1k(
              *(const s16x4*)&ones, *(const s16x4*)&pf[nt], accl, 0, 0, 0);
#pragma unroll
          for (int dt = 0; dt < 4; dt++) {
            bf16x4 av = *(const bf16x4*)(
                Vsc + (dt * 16 + l15) * 140 + nt * 16 + quad * 4);
            acco[dt] = __builtin_amdgcn_mfma_f32_16x16x16bf16_1k(
                *(const s16x4*)&av, *(const s16x4*)&pf[nt], acco[dt], 0, 0, 0);
          }
        }
        __builtin_amdgcn_s_setprio(0);
      }

      // stage prefetched V tile into the other buffer (iter end; the
      // vmcnt wait here also covers the K glds16 issued at iter start)
      if (havenext) {
        int nb = cur ^ 1;
        *(bf16x4*)(Vs[nb] + srow * 140 + scol)          = ((bf16x4*)&vna)[0];
        *(bf16x4*)(Vs[nb] + srow * 140 + scol + 4)      = ((bf16x4*)&vna)[1];
        *(bf16x4*)(Vs[nb] + srow * 140 + 64 + scol)     = ((bf16x4*)&vnb)[0];
        *(bf16x4*)(Vs[nb] + srow * 140 + 64 + scol + 4) = ((bf16x4*)&vnb)[1];
      }
    }

    // epilogue: O^T -> Y [B*T, 1024], 8B stores (4 consecutive d)
    {
      float rcp = 1.f / accl[0];
      int qg = qw + l15;
      size_t base = ((size_t)(b * T_SZ + qg)) * CD + h * HD + quad * 4;
      for (int dt = 0; dt < 4; dt++) {
        bf16x4 o;
        for (int r = 0; r < 4; r++) o[r] = (__bf16)(acco[dt][r] * rcp);
        *(bf16x4*)(Y + base + dt * 16) = o;
      }
    }
  }
}

// ---------------------------------------------------------------------------
extern "C" void kernel_launch(void* const* d_in, const int* in_sizes, int n_in,
                              void* d_out, int out_size, void* d_ws, size_t ws_size,
                              hipStream_t stream) {
  (void)in_sizes; (void)n_in; (void)out_size; (void)ws_size;
  const void* x  = d_in[0];
  const void* Wq = d_in[2];
  const void* bq = d_in[3];
  const void* Wk = d_in[4];
  const void* bk = d_in[5];
  const void* Wv = d_in[6];
  const void* bv = d_in[7];
  const void* Wo = d_in[8];
  const void* bo = d_in[9];

  char* ws = (char*)d_ws;
  const size_t MB = 1024 * 1024;
  __bf16* WqkvT = (__bf16*)(ws + 0 * MB);          // [3072, 1024]
  __bf16* WoT   = (__bf16*)(ws + 6 * MB);
  __bf16* bqkvc = (__bf16*)(ws + 8 * MB);          // [3072]
  __bf16* boc   = (__bf16*)(ws + 8 * MB + 8192);
  int*    flag  = (int*)   (ws + 8 * MB + 65536);
  __bf16* xc    = (__bf16*)(ws + 9 * MB);          // [8192,1024]; reused as Yb
  __bf16* Qb    = (__bf16*)(ws + 25 * MB);         // [B*H,T,64] pre-scaled
  __bf16* Kb    = (__bf16*)(ws + 41 * MB);
  __bf16* Vt_g  = (__bf16*)(ws + 57 * MB);         // [B*H,64,T]
  __bf16* Yb    = xc;                              // xc dead after QKV GEMM

  Ptr4 pw = {{Wq, Wk, Wv, Wo},
             {WqkvT, WqkvT + (size_t)CD * CD, WqkvT + 2 * (size_t)CD * CD, WoT}};
  Ptr4 pb = {{bq, bk, bv, bo}, {bqkvc, bqkvc + CD, bqkvc + 2 * CD, boc}};

  prep<<<5124, dim3(256), 0, stream>>>(x, flag, xc, pw, pb);

  gemm_qkv<<<dim3(24, MROWS / 128), dim3(512), 0, stream>>>(xc, WqkvT, bqkvc,
                                                            Qb, Kb, Vt_g);

  attn<<<dim3(8, B_SZ * NH), dim3(512), 0, stream>>>(Qb, Kb, Vt_g, Yb);

  gemm_out<<<dim3(CD / 128, MROWS / 128), dim3(512), 0, stream>>>(Yb, WoT, boc,
                                                                  d_out, flag);
}

// Round 16
// 263.946 us; speedup vs baseline: 1.4431x; 1.0024x over previous
//
#include <hip/hip_runtime.h>
#include <cstdint>
#include <cstddef>

#define B_SZ 4
#define T_SZ 2048
#define NH 16
#define HD 64
#define CD 1024
#define MROWS (B_SZ*T_SZ)
#define NEG_BIG (-1e30f)
// 0.125 (1/sqrt(64)) * log2(e): fold softmax base-2 conversion into Q prescale
#define Q_SCALE 0.180336880f

typedef __bf16 bf16x8 __attribute__((ext_vector_type(8)));
typedef __bf16 bf16x4 __attribute__((ext_vector_type(4)));
typedef short s16x4 __attribute__((ext_vector_type(4)));
typedef float f32x4 __attribute__((ext_vector_type(4)));

typedef __attribute__((address_space(3))) void* as3p;
typedef const __attribute__((address_space(1))) void* as1p;

__device__ __forceinline__ void glds16(const void* g, void* l) {
  __builtin_amdgcn_global_load_lds((as1p)g, (as3p)l, 16, 0, 0);
}

__device__ __forceinline__ bf16x8 cvt8(const void* src, int isbf, size_t i8) {
  bf16x8 o;
  if (isbf) {
    o = ((const bf16x8*)src)[i8];
  } else {
    const float4* s = (const float4*)((const float*)src + i8 * 8);
    float4 a = s[0], b = s[1];
    o[0] = (__bf16)a.x; o[1] = (__bf16)a.y; o[2] = (__bf16)a.z; o[3] = (__bf16)a.w;
    o[4] = (__bf16)b.x; o[5] = (__bf16)b.y; o[6] = (__bf16)b.z; o[7] = (__bf16)b.w;
  }
  return o;
}

struct Ptr4 { const void* s[4]; __bf16* d[4]; };

// ---------------------------------------------------------------------------
// Fused prep: dtype-detect + x conversion + bias conversion + 4x weight
// transpose-convert, ONE kernel. (unchanged from R14 — passed, saved ~11us)
// blocks 0-4095: conv_in; 4096-4099: bias conv; 4100-5123: transpose(16,16,4).
// ---------------------------------------------------------------------------
__global__ __launch_bounds__(256) void prep(const void* __restrict__ x,
                                            int* __restrict__ flag,
                                            __bf16* __restrict__ xc,
                                            Ptr4 pw, Ptr4 pb) {
  __shared__ int cnt[256];
  const int t = threadIdx.x;
  {
    const uint32_t* xw = (const uint32_t*)x;
    int c = 0;
    for (int i = 0; i < 4; i++) {
      uint32_t wv = xw[t * 4 + i];
      uint32_t e = (wv >> 7) & 0xFF;
      c += (e >= 100 && e <= 140) ? 1 : 0;
    }
    cnt[t] = c;
    __syncthreads();
    for (int s = 128; s > 0; s >>= 1) {
      if (t < s) cnt[t] += cnt[t + s];
      __syncthreads();
    }
  }
  const int isbf = (cnt[0] > 700) ? 1 : 0;
  const int bid = blockIdx.x;
  if (bid == 0 && t == 0) flag[0] = isbf;

  if (bid < 4096) {
    int i = bid * 256 + t;
    ((bf16x8*)xc)[i] = cvt8(x, isbf, i);
  } else if (bid < 4100) {
    int which = bid - 4096;
    if (t < CD / 8)
      ((bf16x8*)pb.d[which])[t] = cvt8(pb.s[which], isbf, t);
  } else {
    __shared__ __align__(16) __bf16 tile[64 * 72];
    int bid2 = bid - 4100;
    const void* W = pw.s[bid2 >> 8];
    __bf16* WT = pw.d[bid2 >> 8];
    const int r0 = ((bid2 >> 4) & 15) * 64, c0 = (bid2 & 15) * 64;
    const int rr = t >> 3, c8 = (t & 7) * 8;
    for (int pp = 0; pp < 2; pp++) {
      int r = pp * 32 + rr;
      *(bf16x8*)(tile + r * 72 + c8) =
          cvt8(W, isbf, ((size_t)(r0 + r) * CD + c0 + c8) / 8);
    }
    __syncthreads();
    for (int pp = 0; pp < 2; pp++) {
      int cc = pp * 32 + rr;
      bf16x8 o;
      for (int j = 0; j < 8; j++) o[j] = tile[(c8 + j) * 72 + cc];
      *(bf16x8*)(WT + (size_t)(c0 + cc) * CD + r0 + c8) = o;
    }
  }
}

// ---------------------------------------------------------------------------
// Fused QKV GEMM: C[8192, 3072] = x @ [WqT;WkT;WvT]^T + bias.
// bn 0-7 -> Q, 8-15 -> K, 16-23 -> V (seg uniform per block).
// 512 threads / 8 waves (2M x 4N), wave tile 64x32, acc[4][2]=32 AGPR.
// BK=128 single 64KB buffer, 8 K-steps (R15: this halved the drain count
// and dropped gemm_qkv out of the profile head). Staging srow16/scolE;
// XOR swizzle store-side via pre-swizzled global col, read-side (l15&7)*8.
// Q/K swapped MFMA -> bf16x4 epilogue stores. (unchanged from R15 — passed)
// ---------------------------------------------------------------------------
__global__ __launch_bounds__(512) void gemm_qkv(
    const __bf16* __restrict__ A, const __bf16* __restrict__ BT,
    const __bf16* __restrict__ bias,
    __bf16* __restrict__ Qb, __bf16* __restrict__ Kb, __bf16* __restrict__ Vt) {
  __shared__ __align__(16) __bf16 As[128 * 128];
  __shared__ __align__(16) __bf16 Bs[128 * 128];
  const int tid = threadIdx.x;
  const int w = tid >> 6, lane = tid & 63;
  const int l15 = lane & 15, quad = lane >> 4;
  const int wm = w & 1, wn = w >> 1;             // wn 0..3
  const int bm = blockIdx.y, bn = blockIdx.x;
  const bool swapped = (bn < 16);        // Q and K segments

  f32x4 acc[4][2];
  for (int i = 0; i < 4; i++)
    for (int j = 0; j < 2; j++) acc[i][j] = (f32x4)0.f;

  const int srow16 = tid >> 4;                   // 0..31
  const int scolE = (tid & 15) * 8;              // 0..120 elems
  const int scolsw = scolE ^ ((srow16 & 7) * 8); // pre-swizzled source col
  const __bf16* Abase = A + (size_t)(bm * 128) * CD;
  const __bf16* Bbase = BT + (size_t)(bn * 128) * CD;

  const int swz = (l15 & 7) * 8;                  // read-side swizzle
  for (int k0 = 0; k0 < CD; k0 += 128) {
    __syncthreads();
    for (int p = 0; p < 4; p++) {
      int row = p * 32 + srow16;
      glds16(Abase + (size_t)row * CD + k0 + scolsw,
             (char*)As + (p * 32 + w * 4) * 256);
      glds16(Bbase + (size_t)row * CD + k0 + scolsw,
             (char*)Bs + (p * 32 + w * 4) * 256);
    }
    __syncthreads();
    for (int kc = 0; kc < 4; kc++) {
      const int koff = (kc * 32 + quad * 8) ^ swz;
      bf16x8 af[4], bfr[2];
      for (int mt = 0; mt < 4; mt++)
        af[mt] = *(const bf16x8*)(As + (wm * 64 + mt * 16 + l15) * 128 + koff);
      for (int nt = 0; nt < 2; nt++)
        bfr[nt] = *(const bf16x8*)(Bs + (wn * 32 + nt * 16 + l15) * 128 + koff);
      if (swapped) {
        for (int mt = 0; mt < 4; mt++)
          for (int nt = 0; nt < 2; nt++)
            acc[mt][nt] = __builtin_amdgcn_mfma_f32_16x16x32_bf16(
                bfr[nt], af[mt], acc[mt][nt], 0, 0, 0);
      } else {
        for (int mt = 0; mt < 4; mt++)
          for (int nt = 0; nt < 2; nt++)
            acc[mt][nt] = __builtin_amdgcn_mfma_f32_16x16x32_bf16(
                af[mt], bfr[nt], acc[mt][nt], 0, 0, 0);
      }
    }
  }

  if (swapped) {
    // C^T frags: reg r -> channel, l15 -> token. 8B stores.
    const int bq_ = bm >> 4;                   // batch (uniform)
    const int tokb = (bm & 15) * 128 + wm * 64;
    __bf16* dst = (bn < 8) ? Qb : Kb;
    const float sc = (bn < 8) ? Q_SCALE : 1.f;
    for (int nt = 0; nt < 2; nt++) {
      const int colb = wn * 32 + nt * 16 + quad * 4;   // 0..127 in block
      const int hq = (bn & 7) * 2 + (colb >> 6);       // head
      const int d0 = colb & 63;
      bf16x4 bv4 = *(const bf16x4*)(bias + bn * 128 + colb);
      for (int mt = 0; mt < 4; mt++) {
        int tok = tokb + mt * 16 + l15;
        bf16x4 o;
        for (int r = 0; r < 4; r++)
          o[r] = (__bf16)((acc[mt][nt][r] + (float)bv4[r]) * sc);
        *(bf16x4*)(dst + ((size_t)(bq_ * NH + hq) * T_SZ + tok) * HD + d0) = o;
      }
    }
  } else {
    // V: normal frags (reg r -> token), store V^T [B*H, 64, T] 8B along tok
    for (int nt = 0; nt < 2; nt++) {
      int col = bn * 128 + wn * 32 + nt * 16 + l15;
      int c = col & 1023, h = c >> 6, d = c & 63;
      float bv = (float)bias[col];
      for (int mt = 0; mt < 4; mt++) {
        int row0 = bm * 128 + wm * 64 + mt * 16 + quad * 4;
        int b = row0 >> 11, tok0 = row0 & 2047;
        bf16x4 o;
        for (int r = 0; r < 4; r++) o[r] = (__bf16)(acc[mt][nt][r] + bv);
        *(bf16x4*)(Vt + ((size_t)((b << 4) + h) * HD + d) * T_SZ + tok0) = o;
      }
    }
  }
}

// ---------------------------------------------------------------------------
// Out-proj GEMM: d_out[8192,1024] = Yb @ WoT^T + bo, output dtype per flag.
// BK=128 port of gemm_qkv's R15 change (proven: halves barrier drains).
// ---------------------------------------------------------------------------
__global__ __launch_bounds__(512) void gemm_out(
    const __bf16* __restrict__ A, const __bf16* __restrict__ BT,
    const __bf16* __restrict__ bias, void* __restrict__ Out,
    const int* __restrict__ flag) {
  __shared__ __align__(16) __bf16 As[128 * 128];
  __shared__ __align__(16) __bf16 Bs[128 * 128];
  const int tid = threadIdx.x;
  const int w = tid >> 6, lane = tid & 63;
  const int l15 = lane & 15, quad = lane >> 4;
  const int wm = w & 1, wn = w >> 1;
  const int bm = blockIdx.y, bn = blockIdx.x;

  f32x4 acc[4][2];
  for (int i = 0; i < 4; i++)
    for (int j = 0; j < 2; j++) acc[i][j] = (f32x4)0.f;

  const int srow16 = tid >> 4;                   // 0..31
  const int scolE = (tid & 15) * 8;
  const int scolsw = scolE ^ ((srow16 & 7) * 8);
  const __bf16* Abase = A + (size_t)(bm * 128) * CD;
  const __bf16* Bbase = BT + (size_t)(bn * 128) * CD;

  const int swz = (l15 & 7) * 8;
  for (int k0 = 0; k0 < CD; k0 += 128) {
    __syncthreads();
    for (int p = 0; p < 4; p++) {
      int row = p * 32 + srow16;
      glds16(Abase + (size_t)row * CD + k0 + scolsw,
             (char*)As + (p * 32 + w * 4) * 256);
      glds16(Bbase + (size_t)row * CD + k0 + scolsw,
             (char*)Bs + (p * 32 + w * 4) * 256);
    }
    __syncthreads();
    for (int kc = 0; kc < 4; kc++) {
      const int koff = (kc * 32 + quad * 8) ^ swz;
      bf16x8 af[4], bfr[2];
      for (int mt = 0; mt < 4; mt++)
        af[mt] = *(const bf16x8*)(As + (wm * 64 + mt * 16 + l15) * 128 + koff);
      for (int nt = 0; nt < 2; nt++)
        bfr[nt] = *(const bf16x8*)(Bs + (wn * 32 + nt * 16 + l15) * 128 + koff);
      for (int mt = 0; mt < 4; mt++)
        for (int nt = 0; nt < 2; nt++)
          acc[mt][nt] = __builtin_amdgcn_mfma_f32_16x16x32_bf16(
              bfr[nt], af[mt], acc[mt][nt], 0, 0, 0);
    }
  }

  const int isbf = flag[0];
  for (int nt = 0; nt < 2; nt++) {
    const int colb = bn * 128 + wn * 32 + nt * 16 + quad * 4;
    bf16x4 bv4 = *(const bf16x4*)(bias + colb);
    for (int mt = 0; mt < 4; mt++) {
      int row = bm * 128 + wm * 64 + mt * 16 + l15;
      if (isbf) {
        bf16x4 o;
        for (int r = 0; r < 4; r++)
          o[r] = (__bf16)(acc[mt][nt][r] + (float)bv4[r]);
        *(bf16x4*)((__bf16*)Out + (size_t)row * CD + colb) = o;
      } else {
        f32x4 o;
        for (int r = 0; r < 4; r++) o[r] = acc[mt][nt][r] + (float)bv4[r];
        *(f32x4*)((float*)Out + (size_t)row * CD + colb) = o;
      }
    }
  }
}

// ---------------------------------------------------------------------------
// Flash attention, causal, transposed-S. Q pre-scaled by 0.125*log2e.
// R15 structure + defer-max THR=8 (T13): skip the O/l rescale unless the
// tile max grew by >8 (log2 units). P bounded by 2^8 — safe in bf16/f32;
// guide-verified (+5% attn, data-independent, HK ships THR=8).
// ---------------------------------------------------------------------------
__global__ __launch_bounds__(512, 4) void attn(
    const __bf16* __restrict__ Q, const __bf16* __restrict__ K,
    const __bf16* __restrict__ Vt, __bf16* __restrict__ Y) {
  __shared__ __align__(16) __bf16 Ks[2][128 * 64];   // swizzled, 16KB each
  __shared__ __align__(16) __bf16 Vs[2][64 * 140];   // [d][key], pitch 140

  const int tid = threadIdx.x, w = tid >> 6, lane = tid & 63;
  const int l15 = lane & 15, quad = lane >> 4;
  const int lid = blockIdx.x + 8 * blockIdx.y;   // gridDim.x == 8
  const int bh = lid & 63;                       // XCD = lid%8 = bh%8
  const int pairi = lid >> 6;                    // 0..7

  const __bf16* Qbh = Q + (size_t)bh * T_SZ * HD;
  const __bf16* Kbh = K + (size_t)bh * T_SZ * HD;
  const __bf16* Vbh = Vt + (size_t)bh * HD * T_SZ;

  const int srow = tid >> 3;          // 0..63
  const int scol = (tid & 7) * 8;     // 0..56
  const int ksrc = scol ^ ((srow & 7) * 8);   // pre-swizzled source column
  const int b = bh >> 4, h = bh & 15;

  bf16x4 ones;
  for (int r = 0; r < 4; r++) ones[r] = (__bf16)1.0f;

  for (int ph = 0; ph < 2; ph++) {
    const int tq = ph ? (15 - pairi) : pairi;
    const int q0 = tq * 128;
    const int niter = tq + 1;
    const int qw = q0 + w * 16;       // wave's first q row

    __syncthreads();   // prior phase fully done with LDS
    // prologue: stage KV tile 0 into buffer 0 (K async, V via regs)
    glds16(Kbh + (size_t)srow * HD + ksrc, (char*)Ks[0] + w * 1024);
    glds16(Kbh + (size_t)(64 + srow) * HD + ksrc,
           (char*)Ks[0] + 8192 + w * 1024);
    {
      bf16x8 va = *(const bf16x8*)(Vbh + (size_t)srow * T_SZ + scol);
      bf16x8 vb = *(const bf16x8*)(Vbh + (size_t)srow * T_SZ + 64 + scol);
      *(bf16x4*)(Vs[0] + srow * 140 + scol)          = ((bf16x4*)&va)[0];
      *(bf16x4*)(Vs[0] + srow * 140 + scol + 4)      = ((bf16x4*)&va)[1];
      *(bf16x4*)(Vs[0] + srow * 140 + 64 + scol)     = ((bf16x4*)&vb)[0];
      *(bf16x4*)(Vs[0] + srow * 140 + 64 + scol + 4) = ((bf16x4*)&vb)[1];
    }

    // Q fragments (B-operand: n=l15->q, k=quad*8+j->d)
    bf16x8 aq[2];
    for (int kc = 0; kc < 2; kc++)
      aq[kc] = *(const bf16x8*)(
          Qbh + (size_t)(qw + l15) * HD + kc * 32 + quad * 8);

    f32x4 acco[4];   // O^T tiles [d16 x q16]: row d=quad*4+r, col q=l15
    for (int dt = 0; dt < 4; dt++) acco[dt] = (f32x4)0.f;
    f32x4 accl = (f32x4)0.f;   // ones-row MFMA: accl[0] = sum_k P[k][q=l15]
    float m_ = NEG_BIG;

    for (int it = 0; it < niter; it++) {
      const int cur = it & 1;
      const int kv0 = it * 128;
      __syncthreads();   // staging for cur drained (syncthreads waits vmcnt)

      // issue async staging of next K tile + reg-prefetch next V tile
      bf16x8 vna, vnb;
      const bool havenext = (it + 1 < niter);
      if (havenext) {
        int kv1 = kv0 + 128;
        glds16(Kbh + (size_t)(kv1 + srow) * HD + ksrc,
               (char*)Ks[cur ^ 1] + w * 1024);
        glds16(Kbh + (size_t)(kv1 + 64 + srow) * HD + ksrc,
               (char*)Ks[cur ^ 1] + 8192 + w * 1024);
        vna = *(const bf16x8*)(Vbh + (size_t)srow * T_SZ + kv1 + scol);
        vnb = *(const bf16x8*)(Vbh + (size_t)srow * T_SZ + kv1 + 64 + scol);
      }

      {
        const __bf16* Ksc = Ks[cur];
        const __bf16* Vsc = Vs[cur];

        // S^T = K Q^T : tiles [key16 x q16]; row key=quad*4+r, col q=l15
        f32x4 accs[8];
        for (int nt = 0; nt < 8; nt++) accs[nt] = (f32x4)0.f;
        const int swz = (l15 & 7) * 8;     // K read swizzle (row&7 == l15&7)
        __builtin_amdgcn_s_setprio(1);
        for (int kc = 0; kc < 2; kc++)
          for (int nt = 0; nt < 8; nt++) {
            bf16x8 ak = *(const bf16x8*)(
                Ksc + (nt * 16 + l15) * 64 + ((kc * 32 + quad * 8) ^ swz));
            accs[nt] = __builtin_amdgcn_mfma_f32_16x16x32_bf16(
                ak, aq[kc], accs[nt], 0, 0, 0);
          }
        __builtin_amdgcn_s_setprio(0);

        // causal mask (only the diagonal tile: kv0 == q0)
        if (kv0 + 127 > qw) {
          int qg = qw + l15;
          for (int nt = 0; nt < 8; nt++) {
            int kg0 = kv0 + nt * 16 + quad * 4;
            for (int r = 0; r < 4; r++)
              if (kg0 + r > qg) accs[nt][r] = NEG_BIG;
          }
        }

        // local max: per-tile max4 then tree + cross-quad shfl_xor
        float tm[8];
        for (int nt = 0; nt < 8; nt++)
          tm[nt] = fmaxf(fmaxf(accs[nt][0], accs[nt][1]),
                         fmaxf(accs[nt][2], accs[nt][3]));
        float u0 = fmaxf(fmaxf(tm[0], tm[1]), fmaxf(tm[2], tm[3]));
        float u1 = fmaxf(fmaxf(tm[4], tm[5]), fmaxf(tm[6], tm[7]));
        float mloc = fmaxf(u0, u1);
        mloc = fmaxf(mloc, __shfl_xor(mloc, 16));
        mloc = fmaxf(mloc, __shfl_xor(mloc, 32));

        // defer-max (T13, THR=8): rescale only when the max grew by >8.
        // Keeping m_ bounds P by 2^8 — safe in bf16/f32 accum.
        if (!__all(mloc - m_ <= 8.f)) {
          float mnew = fmaxf(m_, mloc);
          float alpha = __builtin_amdgcn_exp2f(m_ - mnew);
          m_ = mnew;
          accl[0] *= alpha;
          for (int dt = 0; dt < 4; dt++)
            for (int r = 0; r < 4; r++) acco[dt][r] *= alpha;
        }

        // P^T = exp2(S^T - m): stays in regs as x16 B-operand fragments
        bf16x4 pf[8];
        for (int nt = 0; nt < 8; nt++)
          for (int r = 0; r < 4; r++)
            pf[nt][r] = (__bf16)__builtin_amdgcn_exp2f(accs[nt][r] - m_);

        // O^T += V^T P^T; l-row via ones-A MFMA (dt==4 virtual tile)
        __builtin_amdgcn_s_setprio(1);
#pragma unroll
        for (int nt = 0; nt < 8; nt++) {
          accl = __builtin_amdgcn_mfma_f32_16x16x16bf16_1k(
              *(const s16x4*)&ones, *(const s16x4*)&pf[nt], accl, 0, 0, 0);
#pragma unroll
          for (int dt = 0; dt < 4; dt++) {
            bf16x4 av = *(const bf16x4*)(
                Vsc + (dt * 16 + l15) * 140 + nt * 16 + quad * 4);
            acco[dt] = __builtin_amdgcn_mfma_f32_16x16x16bf16_1k(
                *(const s16x4*)&av, *(const s16x4*)&pf[nt], acco[dt], 0, 0, 0);
          }
        }
        __builtin_amdgcn_s_setprio(0);
      }

      // stage prefetched V tile into the other buffer (iter end; the
      // vmcnt wait here also covers the K glds16 issued at iter start)
      if (havenext) {
        int nb = cur ^ 1;
        *(bf16x4*)(Vs[nb] + srow * 140 + scol)          = ((bf16x4*)&vna)[0];
        *(bf16x4*)(Vs[nb] + srow * 140 + scol + 4)      = ((bf16x4*)&vna)[1];
        *(bf16x4*)(Vs[nb] + srow * 140 + 64 + scol)     = ((bf16x4*)&vnb)[0];
        *(bf16x4*)(Vs[nb] + srow * 140 + 64 + scol + 4) = ((bf16x4*)&vnb)[1];
      }
    }

    // epilogue: O^T -> Y [B*T, 1024], 8B stores (4 consecutive d)
    {
      float rcp = 1.f / accl[0];
      int qg = qw + l15;
      size_t base = ((size_t)(b * T_SZ + qg)) * CD + h * HD + quad * 4;
      for (int dt = 0; dt < 4; dt++) {
        bf16x4 o;
        for (int r = 0; r < 4; r++) o[r] = (__bf16)(acco[dt][r] * rcp);
        *(bf16x4*)(Y + base + dt * 16) = o;
      }
    }
  }
}

// ---------------------------------------------------------------------------
extern "C" void kernel_launch(void* const* d_in, const int* in_sizes, int n_in,
                              void* d_out, int out_size, void* d_ws, size_t ws_size,
                              hipStream_t stream) {
  (void)in_sizes; (void)n_in; (void)out_size; (void)ws_size;
  const void* x  = d_in[0];
  const void* Wq = d_in[2];
  const void* bq = d_in[3];
  const void* Wk = d_in[4];
  const void* bk = d_in[5];
  const void* Wv = d_in[6];
  const void* bv = d_in[7];
  const void* Wo = d_in[8];
  const void* bo = d_in[9];

  char* ws = (char*)d_ws;
  const size_t MB = 1024 * 1024;
  __bf16* WqkvT = (__bf16*)(ws + 0 * MB);          // [3072, 1024]
  __bf16* WoT   = (__bf16*)(ws + 6 * MB);
  __bf16* bqkvc = (__bf16*)(ws + 8 * MB);          // [3072]
  __bf16* boc   = (__bf16*)(ws + 8 * MB + 8192);
  int*    flag  = (int*)   (ws + 8 * MB + 65536);
  __bf16* xc    = (__bf16*)(ws + 9 * MB);          // [8192,1024]; reused as Yb
  __bf16* Qb    = (__bf16*)(ws + 25 * MB);         // [B*H,T,64] pre-scaled
  __bf16* Kb    = (__bf16*)(ws + 41 * MB);
  __bf16* Vt_g  = (__bf16*)(ws + 57 * MB);         // [B*H,64,T]
  __bf16* Yb    = xc;                              // xc dead after QKV GEMM

  Ptr4 pw = {{Wq, Wk, Wv, Wo},
             {WqkvT, WqkvT + (size_t)CD * CD, WqkvT + 2 * (size_t)CD * CD, WoT}};
  Ptr4 pb = {{bq, bk, bv, bo}, {bqkvc, bqkvc + CD, bqkvc + 2 * CD, boc}};

  prep<<<5124, dim3(256), 0, stream>>>(x, flag, xc, pw, pb);

  gemm_qkv<<<dim3(24, MROWS / 128), dim3(512), 0, stream>>>(xc, WqkvT, bqkvc,
                                                            Qb, Kb, Vt_g);

  attn<<<dim3(8, B_SZ * NH), dim3(512), 0, stream>>>(Qb, Kb, Vt_g, Yb);

  gemm_out<<<dim3(CD / 128, MROWS / 128), dim3(512), 0, stream>>>(Yb, WoT, boc,
                                                                  d_out, flag);
}